// Round 17
// baseline (568.276 us; speedup 1.0000x reference)
//
#include <hip/hip_runtime.h>
#include <hip/hip_bf16.h>
#include <cstdint>
#include <cstddef>

#define BATCH   8
#define NNODES  4095
#define HD      512
#define ID      512
#define LDG     1536   // gate weight leading dim (3H)
#define MAXR    8192   // max parent rows per parity (level 10 parents: 1024 x 8)

typedef unsigned short ushort_t;
typedef __attribute__((ext_vector_type(8))) short  bf16x8;
typedef __attribute__((ext_vector_type(4))) float  f32x4;

// ---------- helpers ----------
__device__ __forceinline__ float bf2f(unsigned short u){
  union { uint32_t i; float f; } v; v.i = ((uint32_t)u) << 16; return v.f;
}
__device__ __forceinline__ unsigned short f2bf(float f){
  union { float f; uint32_t i; } v; v.f = f;
  uint32_t r = v.i + 0x7fffu + ((v.i >> 16) & 1u);
  return (unsigned short)(r >> 16);
}
__device__ __forceinline__ float sigm(float x){ return 1.0f/(1.0f + __expf(-x)); }
__device__ __forceinline__ float tanh_(float x){ return 1.0f - 2.0f/(__expf(2.0f*x)+1.0f); }

// async global->LDS, 16B per lane. lds base must be wave-uniform.
#define GLOAD16(g, l) __builtin_amdgcn_global_load_lds(                      \
    (const __attribute__((address_space(1))) void*)(g),                      \
    (__attribute__((address_space(3))) void*)(l), 16, 0, 0)

// counted-vmcnt pipeline primitives (T3/T4)
#define WAIT_VM(N)  asm volatile("s_waitcnt vmcnt(" #N ")" ::: "memory")
#define WAIT_LGKM0  asm volatile("s_waitcnt lgkmcnt(0)" ::: "memory")
#define SBAR        __builtin_amdgcn_s_barrier()
#define SCHEDB      __builtin_amdgcn_sched_barrier(0)

// chunked bijective XCD swizzle (requires nwg % 8 == 0)
__device__ __forceinline__ int xcd_swz(int orig, int nwg){
  return (orig & 7) * (nwg >> 3) + (orig >> 3);
}

// ---- LDS bank swizzle for [r][32]-ushort (64B-row) staging tiles ----
// write: global_load_lds puts lane l at lds[base + (l>>2)][(l&3)*8] (linear).
// we pre-permute the GLOBAL source chunk so lds[r][s] holds chunk (s-(r&15)>>1)&3;
// read slot for chunk fq at row (..&15)=fr is  sl=(fq+(fr>>1))&3.
// PROVEN conflict-free (round-0: SQ_LDS_BANK_CONFLICT == 0).
// NOTE (round-11/15 lesson): counted-vmcnt across barriers requires every
// in-flight stage to target a buffer NOT read in the next window. Double-kt
// needs 3 buffers on the re-read side (proven: gates -8.6us, cell -16us).

// =======================================================================
// Layouts:
//  Gx  bf16[32768][1536] = X@Wg_ih + bg   (row = node*8+b)
//  Cx  bf16[32768][512]  = X@Wc_ih + bc
//  WgThh bf16[3072][512]: rows [0,1536) = Wg_l^T, [1536,3072) = Wg_r^T
//  WcThh bf16[1024][512]: rows [0,512) = Wc_l^T, [512,1024) = Wc_r^T
//  H ping-pong bf16[MAXR][512]; Ubuf bf16[2][MAXR][512]
//  Parent-row identity (all levels): node = s+t -> parent H-row = (t>>1)*8+b
// =======================================================================

// ---- merged prep (weight transpose+convert) + X gather: one dispatch ----
__global__ __launch_bounds__(256)
void prep_gather(const float* __restrict__ X, ushort_t* __restrict__ Abf,
                 const float* __restrict__ Wg_ih, const float* __restrict__ Wc_ih,
                 const float* __restrict__ Wg_l,  const float* __restrict__ Wg_r,
                 const float* __restrict__ Wc_l,  const float* __restrict__ Wc_r,
                 ushort_t* __restrict__ WgTih, ushort_t* __restrict__ WcTih,
                 ushort_t* __restrict__ WgThh, ushort_t* __restrict__ WcThh)
{
  __shared__ float t[64][65];
  const int bid = blockIdx.x;
  if (bid < 16380){
    const size_t i = (size_t)bid*256 + threadIdx.x;
    const int row = (int)(i >> 7);
    const int c4  = ((int)i & 127)*4;
    const int node = row >> 3, b = row & 7;
    float4 v = *(const float4*)&X[((size_t)b*NNODES + node)*ID + c4];
    ushort4 o = { f2bf(v.x), f2bf(v.y), f2bf(v.z), f2bf(v.w) };
    *(ushort4*)&Abf[(size_t)row*512 + c4] = o;
    return;
  }
  const int pid  = bid - 16380;          // 0..1151
  const int px   = pid % 24;
  const int py   = (pid / 24) & 7;
  const int zsel = pid / 192;            // 0..5
  const float* W; ushort_t* D; int N;
  switch (zsel){
    case 0: W = Wg_ih; D = WgTih;                        N = 1536; break;
    case 1: W = Wc_ih; D = WcTih;                        N = 512;  break;
    case 2: W = Wg_l;  D = WgThh;                        N = 1536; break;
    case 3: W = Wg_r;  D = WgThh + (size_t)1536*512;     N = 1536; break;
    case 4: W = Wc_l;  D = WcThh;                        N = 512;  break;
    default:W = Wc_r;  D = WcThh + (size_t)512*512;      N = 512;  break;
  }
  const int n0 = px*64;
  if (n0 >= N) return;
  const int k0 = py*64;
  const int c = threadIdx.x & 63, rq = threadIdx.x >> 6;
  #pragma unroll
  for (int q = 0; q < 16; ++q){
    int r = q*4 + rq;
    t[r][c] = W[(size_t)(k0 + r)*N + n0 + c];
  }
  __syncthreads();
  #pragma unroll
  for (int q = 0; q < 16; ++q){
    int r = q*4 + rq;
    D[(size_t)(n0 + r)*512 + k0 + c] = f2bf(t[c][r]);
  }
}

// ---- merged hoist GEMM: 256x256 tile, BK=32, double-kt (A 3-buf, B 2-buf) ----
//  80KB LDS -> 2 blocks/CU (2x80 = 160KB exactly). 64 MFMA per barrier pair.
//  Ledger: per it consume A(2it)->a0,(2it+1)->a1 + B0,B1; stage after mid-bar
//  B(2it+2)->B0, B(2it+3)->B1, A(2it+3)->a0, A(2it+4)->a1; WAIT_VM(2) leaves
//  only A(2it+4) (read at it+2) in flight.
__global__ __launch_bounds__(512, 2)
void gemm_hoist(const ushort_t* __restrict__ A,
                const ushort_t* __restrict__ BTg, const float* __restrict__ bg,
                ushort_t* __restrict__ Gx,
                const ushort_t* __restrict__ BTc, const float* __restrict__ bc,
                ushort_t* __restrict__ Cx)
{
  __shared__ __align__(16) ushort_t SH[40960];   // 80KB
  ushort_t (*Al)[256][32] = (ushort_t (*)[256][32])SH;            // 3 x 16KB
  ushort_t (*Bl)[256][32] = (ushort_t (*)[256][32])(SH + 24576);  // 2 x 16KB
  const int wg = xcd_swz(blockIdx.x, gridDim.x);
  const ushort_t* BT; const float* bias; ushort_t* C; int N, m0, n0;
  if (wg < 768){ BT = BTg; bias = bg; C = Gx; N = 1536;
                 m0 = (wg/6)*256; n0 = (wg%6)*256; }
  else         { BT = BTc; bias = bc; C = Cx; N = 512;
                 const int t = wg - 768; m0 = (t>>1)*256; n0 = (t&1)*256; }
  const int tid = threadIdx.x, lane = tid & 63, wave = tid >> 6;
  const ushort_t* Abase = A + (size_t)m0*512;
  const ushort_t* Bbase = BT + (size_t)n0*512;
  const int wr = wave >> 2, wc = wave & 3;              // 2 x 4 wave grid
  const int fr = lane & 15, fq = lane >> 4;
  const int lr = lane >> 2;
  const int cs = ((lane & 3) - (lr >> 1)) & 3;          // swizzled source chunk
  const size_t lo = (size_t)lr*512 + (size_t)cs*8;      // per-lane global offset
  const int sl = (fq + (fr >> 1)) & 3;                  // swizzled read slot
  f32x4 acc[8][4] = {};

  auto stageA = [&](int buf, int kt){    // 2 gloads / thread (256x32 tile)
    const int k0 = kt*32;
    #pragma unroll
    for (int q = 0; q < 2; ++q){
      const int r0 = (wave*2 + q)*16;
      GLOAD16(Abase + (size_t)r0*512 + k0 + lo, &Al[buf][r0][0]);
    }
  };
  auto stageB = [&](int buf, int kt){    // 2 gloads / thread
    const int k0 = kt*32;
    #pragma unroll
    for (int q = 0; q < 2; ++q){
      const int r0 = (wave*2 + q)*16;
      GLOAD16(Bbase + (size_t)r0*512 + k0 + lo, &Bl[buf][r0][0]);
    }
  };

  // prologue: B(0)->B0, B(1)->B1, A(0..2)->buf0..2; VM(2) leaves A(2) flying
  stageB(0, 0); stageB(1, 1);
  stageA(0, 0); stageA(1, 1); stageA(2, 2);
  WAIT_VM(2); SCHEDB; SBAR;

  for (int it = 0; it < 8; ++it){
    const int a0 = (2*it) % 3, a1 = (2*it + 1) % 3;
    bf16x8 af[8], bfr[4];
    // half A: kt = 2it (A-buf a0, B-buf 0)
    #pragma unroll
    for (int i = 0; i < 8; i++)
      af[i] = *(const bf16x8*)&Al[a0][wr*128 + i*16 + fr][sl*8];
    #pragma unroll
    for (int j = 0; j < 4; j++)
      bfr[j] = *(const bf16x8*)&Bl[0][wc*64 + j*16 + fr][sl*8];
    WAIT_LGKM0; SCHEDB;
    __builtin_amdgcn_s_setprio(1);
    #pragma unroll
    for (int i = 0; i < 8; i++)
      #pragma unroll
      for (int j = 0; j < 4; j++)
        acc[i][j] = __builtin_amdgcn_mfma_f32_16x16x32_bf16(af[i], bfr[j], acc[i][j], 0,0,0);
    __builtin_amdgcn_s_setprio(0);
    // half B reads: kt = 2it+1 (A-buf a1, B-buf 1), reuse frag regs
    #pragma unroll
    for (int i = 0; i < 8; i++)
      af[i] = *(const bf16x8*)&Al[a1][wr*128 + i*16 + fr][sl*8];
    #pragma unroll
    for (int j = 0; j < 4; j++)
      bfr[j] = *(const bf16x8*)&Bl[1][wc*64 + j*16 + fr][sl*8];
    WAIT_LGKM0; SCHEDB; SBAR;          // all waves done reading all 4 regions
    if (2*it + 2 < 16) stageB(0, 2*it + 2);
    if (2*it + 3 < 16) stageB(1, 2*it + 3);
    if (2*it + 3 < 16) stageA(a0, 2*it + 3);   // (2it+3)%3 == a0
    if (2*it + 4 < 16) stageA(a1, 2*it + 4);   // (2it+4)%3 == a1
    __builtin_amdgcn_s_setprio(1);
    #pragma unroll
    for (int i = 0; i < 8; i++)
      #pragma unroll
      for (int j = 0; j < 4; j++)
        acc[i][j] = __builtin_amdgcn_mfma_f32_16x16x32_bf16(af[i], bfr[j], acc[i][j], 0,0,0);
    __builtin_amdgcn_s_setprio(0);
    if (2*it + 4 < 16){ WAIT_VM(2); } else { WAIT_VM(0); }
    SCHEDB; SBAR;
  }

  // epilogue: 4 passes of 64 rows via float CT [64][256] with XOR swizzle
  float* CT = (float*)SH;
  const int er = tid >> 3;          // 0..63
  const int ec = tid & 7;           // 0..7
  #pragma unroll
  for (int p = 0; p < 4; ++p){
    __syncthreads();
    #pragma unroll
    for (int i2 = 0; i2 < 2; ++i2){
      const int i = p*2 + i2;
      #pragma unroll
      for (int j = 0; j < 4; ++j){
        const int cc = wc*64 + j*16 + fr;
        const float bv = bias[n0 + cc];
        #pragma unroll
        for (int r = 0; r < 4; ++r){
          const int crow = wr*32 + i2*16 + fq*4 + r;
          CT[crow*256 + (cc ^ ((crow & 7) << 2))] = acc[i][j][r] + bv;
        }
      }
    }
    __syncthreads();
    const int grow = m0 + p*32 + (er >> 5)*128 + (er & 31);
    ushort_t* Crow = C + (size_t)grow*N + n0;
    const int rx = (er & 7) << 2;
    #pragma unroll
    for (int q = 0; q < 8; ++q){
      const int c0 = ec*4 + q*32;
      float4 v = *(const float4*)&CT[er*256 + (c0 ^ rx)];
      ushort4 o = { f2bf(v.x), f2bf(v.y), f2bf(v.z), f2bf(v.w) };
      *(ushort4*)&Crow[c0] = o;
    }
  }
}

// ---- gates_rp: U = sigm(Hprev@Wg_hh[rp] + gx_rp) * ph ----
// double-kt: 8 iterations x {2x16 MFMA, 2 barriers}; 3-buffer rotation,
// steady-state VM(4) ledger verified (round-10: -8.6 us).
__global__ __launch_bounds__(256)
void gates_rp(const ushort_t* __restrict__ Hprev, const ushort_t* __restrict__ WgThh,
              const ushort_t* __restrict__ Gx, ushort_t* __restrict__ Ubuf, int s)
{
  __shared__ __align__(16) ushort_t Al[3][128][32];
  __shared__ __align__(16) ushort_t Bl[3][128][32];
  const int wg = xcd_swz(blockIdx.x, gridDim.x);
  const int n0 = (wg & 3)*128;
  const int z  = (wg >> 2) & 1;
  const int m0 = (wg >> 3)*128;
  const int tid = threadIdx.x, lane = tid & 63, wave = tid >> 6;
  const ushort_t* Abase = Hprev + (size_t)m0*512;
  const ushort_t* Bbase = WgThh + ((size_t)z*1536 + n0)*512;
  const int wr = wave >> 1, wc = wave & 1;
  const int fr = lane & 15, fq = lane >> 4;
  const int lr = lane >> 2;
  const int cs = ((lane & 3) - (lr >> 1)) & 3;
  const size_t lo = (size_t)lr*512 + cs*8;
  const int sl = (fq + (fr >> 1)) & 3;
  f32x4 acc[4][4] = {};

  auto stage = [&](int buf, int kt){
    const int k0 = kt*32;
    #pragma unroll
    for (int q = 0; q < 2; ++q){
      int r = q*64 + wave*16;
      GLOAD16(Abase + (size_t)r*512 + k0 + lo, &Al[buf][r][0]);
      GLOAD16(Bbase + (size_t)r*512 + k0 + lo, &Bl[buf][r][0]);
    }
  };

  stage(0, 0); stage(1, 1); stage(2, 2);
  WAIT_VM(4); SCHEDB; SBAR;          // buffers 0,1 landed; 2 in flight
  for (int it = 0; it < 8; ++it){
    const int cur = (2*it) % 3, nxt = (2*it + 1) % 3;
    bf16x8 af[4], bfr[4];
    #pragma unroll
    for (int i = 0; i < 4; i++){
      af[i]  = *(const bf16x8*)&Al[cur][wr*64 + i*16 + fr][sl*8];
      bfr[i] = *(const bf16x8*)&Bl[cur][wc*64 + i*16 + fr][sl*8];
    }
    WAIT_LGKM0; SCHEDB;
    __builtin_amdgcn_s_setprio(1);
    #pragma unroll
    for (int i = 0; i < 4; i++)
      #pragma unroll
      for (int j = 0; j < 4; j++)
        acc[i][j] = __builtin_amdgcn_mfma_f32_16x16x32_bf16(af[i], bfr[j], acc[i][j], 0,0,0);
    __builtin_amdgcn_s_setprio(0);
    #pragma unroll
    for (int i = 0; i < 4; i++){
      af[i]  = *(const bf16x8*)&Al[nxt][wr*64 + i*16 + fr][sl*8];
      bfr[i] = *(const bf16x8*)&Bl[nxt][wc*64 + i*16 + fr][sl*8];
    }
    WAIT_LGKM0; SCHEDB; SBAR;        // all waves done reading cur & nxt
    if (2*it + 3 < 16) stage(cur, 2*it + 3);
    if (2*it + 4 < 16) stage(nxt, 2*it + 4);
    __builtin_amdgcn_s_setprio(1);
    #pragma unroll
    for (int i = 0; i < 4; i++)
      #pragma unroll
      for (int j = 0; j < 4; j++)
        acc[i][j] = __builtin_amdgcn_mfma_f32_16x16x32_bf16(af[i], bfr[j], acc[i][j], 0,0,0);
    __builtin_amdgcn_s_setprio(0);
    if (2*it + 4 < 16){ WAIT_VM(4); } else { WAIT_VM(0); }
    SCHEDB; SBAR;
  }

  #pragma unroll
  for (int i = 0; i < 4; i++)
    #pragma unroll
    for (int j = 0; j < 4; j++){
      const int col = n0 + wc*64 + j*16 + fr;      // 0..511
      #pragma unroll
      for (int r = 0; r < 4; r++){
        const int m = m0 + wr*64 + i*16 + fq*4 + r;
        const int t = m >> 3, b = m & 7;
        const int node = s + 2*t + z;
        const float gx = bf2f(Gx[(size_t)(node*8 + b)*1536 + col]);
        const float ph = bf2f(Hprev[(size_t)m*512 + col]);
        Ubuf[((size_t)z*MAXR + m)*512 + col] = f2bf(sigm(acc[i][j][r] + gx) * ph);
      }
    }
}

// ---- cell_comb: fused 3-GEMM + combine, double-kt (A 3-buf, B 2-buf) ----
// (round-15 verified: -16 us)
__global__ __launch_bounds__(256)
void cell_comb(const ushort_t* __restrict__ Ubuf, const ushort_t* __restrict__ Hprev,
               const ushort_t* __restrict__ WcThh, const ushort_t* __restrict__ WgThh,
               const ushort_t* __restrict__ Gx, const ushort_t* __restrict__ Cx,
               float* __restrict__ out, ushort_t* __restrict__ Hcur,
               int s, int writeH)
{
  __shared__ __align__(16) ushort_t Ul[3][128][32];   // 24KB
  __shared__ __align__(16) ushort_t Hl[3][128][32];   // 24KB
  __shared__ __align__(16) ushort_t Bc[2][64][32];    // 8KB
  __shared__ __align__(16) ushort_t Bp[2][64][32];    // 8KB
  __shared__ __align__(16) ushort_t Bz[2][64][32];    // 8KB  (total 72KB)
  const int wg = xcd_swz(blockIdx.x, gridDim.x);
  const int n0 = (wg & 7)*64;
  const int z  = (wg >> 3) & 1;
  const int m0 = (wg >> 4)*128;
  const int tid = threadIdx.x, lane = tid & 63, wave = tid >> 6;
  const int wr = wave >> 1, wc = wave & 1;
  const int fr = lane & 15, fq = lane >> 4;
  const int lr = lane >> 2;
  const int cs = ((lane & 3) - (lr >> 1)) & 3;
  const int lc = cs*8;
  const int sl = (fq + (fr >> 1)) & 3;

  const ushort_t* Ab  = Ubuf  + ((size_t)z*MAXR + m0)*512;
  const ushort_t* Hb  = Hprev + (size_t)m0*512;
  const ushort_t* Bcb = WcThh + ((size_t)z*512  + n0)*512;
  const ushort_t* Bpb = WgThh + ((size_t)z*1536 + 512  + n0)*512;
  const ushort_t* Bzb = WgThh + ((size_t)z*1536 + 1024 + n0)*512;

  f32x4 acc_c[4][2] = {}, acc_p[4][2] = {}, acc_z[4][2] = {};

  auto stageA = [&](int buf, int kt){    // 4 gloads / thread (Ul + Hl)
    const int k0 = kt*32;
    #pragma unroll
    for (int q = 0; q < 2; ++q){
      const int r = q*64 + wave*16;
      GLOAD16(Ab + (size_t)(r + lr)*512 + k0 + lc, &Ul[buf][r][0]);
      GLOAD16(Hb + (size_t)(r + lr)*512 + k0 + lc, &Hl[buf][r][0]);
    }
  };
  auto stageB = [&](int buf, int kt){    // 3 gloads / thread (Bc,Bp,Bz)
    const int k0 = kt*32;
    const int r2 = wave*16;
    GLOAD16(Bcb + (size_t)(r2 + lr)*512 + k0 + lc, &Bc[buf][r2][0]);
    GLOAD16(Bpb + (size_t)(r2 + lr)*512 + k0 + lc, &Bp[buf][r2][0]);
    GLOAD16(Bzb + (size_t)(r2 + lr)*512 + k0 + lc, &Bz[buf][r2][0]);
  };

  auto read_frags = [&](int abuf, int bbuf, bf16x8 au[4], bf16x8 ah[4],
                        bf16x8 bc2[2], bf16x8 bp2[2], bf16x8 bz2[2]){
    #pragma unroll
    for (int i = 0; i < 4; i++){
      au[i] = *(const bf16x8*)&Ul[abuf][wr*64 + i*16 + fr][sl*8];
      ah[i] = *(const bf16x8*)&Hl[abuf][wr*64 + i*16 + fr][sl*8];
    }
    #pragma unroll
    for (int j = 0; j < 2; j++){
      bc2[j] = *(const bf16x8*)&Bc[bbuf][wc*32 + j*16 + fr][sl*8];
      bp2[j] = *(const bf16x8*)&Bp[bbuf][wc*32 + j*16 + fr][sl*8];
      bz2[j] = *(const bf16x8*)&Bz[bbuf][wc*32 + j*16 + fr][sl*8];
    }
  };

  // prologue: B first, then A, so VM(4) leaves exactly A(2) in flight
  stageB(0, 0); stageB(1, 1);
  stageA(0, 0); stageA(1, 1); stageA(2, 2);
  WAIT_VM(4); SCHEDB; SBAR;            // B(0),B(1),A(0),A(1) landed; A(2) flying

  for (int it = 0; it < 8; ++it){
    const int a0 = (2*it) % 3, a1 = (2*it + 1) % 3;
    bf16x8 au[4], ah[4], bc2[2], bp2[2], bz2[2];
    read_frags(a0, 0, au, ah, bc2, bp2, bz2);
    WAIT_LGKM0; SCHEDB;
    __builtin_amdgcn_s_setprio(1);
    #pragma unroll
    for (int i = 0; i < 4; i++)
      #pragma unroll
      for (int j = 0; j < 2; j++){
        acc_c[i][j] = __builtin_amdgcn_mfma_f32_16x16x32_bf16(au[i], bc2[j], acc_c[i][j], 0,0,0);
        acc_p[i][j] = __builtin_amdgcn_mfma_f32_16x16x32_bf16(ah[i], bp2[j], acc_p[i][j], 0,0,0);
        acc_z[i][j] = __builtin_amdgcn_mfma_f32_16x16x32_bf16(ah[i], bz2[j], acc_z[i][j], 0,0,0);
      }
    __builtin_amdgcn_s_setprio(0);
    read_frags(a1, 1, au, ah, bc2, bp2, bz2);
    WAIT_LGKM0; SCHEDB; SBAR;          // all waves done reading both halves
    if (2*it + 2 < 16) stageB(0, 2*it + 2);
    if (2*it + 3 < 16) stageB(1, 2*it + 3);
    if (2*it + 3 < 16) stageA(a0, 2*it + 3);   // (2it+3)%3 == a0
    if (2*it + 4 < 16) stageA(a1, 2*it + 4);   // (2it+4)%3 == a1
    __builtin_amdgcn_s_setprio(1);
    #pragma unroll
    for (int i = 0; i < 4; i++)
      #pragma unroll
      for (int j = 0; j < 2; j++){
        acc_c[i][j] = __builtin_amdgcn_mfma_f32_16x16x32_bf16(au[i], bc2[j], acc_c[i][j], 0,0,0);
        acc_p[i][j] = __builtin_amdgcn_mfma_f32_16x16x32_bf16(ah[i], bp2[j], acc_p[i][j], 0,0,0);
        acc_z[i][j] = __builtin_amdgcn_mfma_f32_16x16x32_bf16(ah[i], bz2[j], acc_z[i][j], 0,0,0);
      }
    __builtin_amdgcn_s_setprio(0);
    if (2*it + 4 < 16){ WAIT_VM(4); } else { WAIT_VM(0); }
    SCHEDB; SBAR;
  }

  #pragma unroll
  for (int i = 0; i < 4; i++)
    #pragma unroll
    for (int j = 0; j < 2; j++){
      const int col = n0 + wc*32 + j*16 + fr;     // 0..511
      #pragma unroll
      for (int r = 0; r < 4; r++){
        const int m = m0 + wr*64 + i*16 + fq*4 + r;
        const int t = m >> 3, b = m & 7;
        const int node = s + 2*t + z;
        const size_t crow = (size_t)node*8 + b;
        const float cell = tanh_(acc_c[i][j][r] + bf2f(Cx[crow*512 + col]));
        const float zp   = sigm(acc_p[i][j][r] + bf2f(Gx[crow*1536 + 512  + col]));
        const float zv   = sigm(acc_z[i][j][r] + bf2f(Gx[crow*1536 + 1024 + col]));
        // parent h: for node = s+2t+z, parent_local = t -> Hprev row = t*8+b = m
        const float ph = bf2f(Hprev[(size_t)m*512 + col]);
        const float h  = zp*ph + zv*cell;
        out[((size_t)b*NNODES + node - 1)*HD + col] = h;
        if (writeH) Hcur[(size_t)((2*t + z)*8 + b)*512 + col] = f2bf(h);
      }
    }
}

// ---- root: h0 = sigm(gx_z) * tanh(cx) ----
__global__ void root_k(const ushort_t* __restrict__ Gx, const ushort_t* __restrict__ Cx,
                       float* __restrict__ out, ushort_t* __restrict__ H0)
{
  const int b = blockIdx.x, c = threadIdx.x;
  float zv   = sigm(bf2f(Gx[(size_t)b*1536 + 1024 + c]));
  float cell = tanh_(bf2f(Cx[(size_t)b*512 + c]));
  float h = zv * cell;
  out[((size_t)b*NNODES + (NNODES-1))*HD + c] = h;
  out[(size_t)BATCH*NNODES*HD + (size_t)b*HD + c] = h;
  H0[(size_t)b*512 + c] = f2bf(h);
}

// ---- small levels (d=1..6): 8-way K-split, 1024-thread blocks ----
// Parent h read from Hprev (bf16, coalesced): node = s+t -> H-row (t>>1)*8+b.
__global__ __launch_bounds__(1024)
void small_gates2(const ushort_t* __restrict__ Hprev, const ushort_t* __restrict__ Gx,
    const float* __restrict__ Wg_l, const float* __restrict__ Wg_r,
    float* __restrict__ G, float* __restrict__ Uf, int s)
{
  __shared__ float PHl[8][512];        // 16KB
  __shared__ float red[8][8][128];     // 32KB: [ks][b][colq]
  const int t = blockIdx.x, node = s + t;
  const int tid  = threadIdx.x;        // 0..1023
  const int colq = tid & 127;
  const int ks   = tid >> 7;           // 0..7
  const int col  = blockIdx.y*128 + colq;   // 0..1535
  const int prow0 = (t >> 1)*8;        // parent H base row
  for (int idx = tid; idx < 8*512; idx += 1024){
    int b = idx >> 9, k = idx & 511;
    PHl[b][k] = bf2f(Hprev[(size_t)(prow0 + b)*512 + k]);
  }
  __syncthreads();
  const float* Whh = (node & 1) ? Wg_l : Wg_r;
  float acc[8] = {};
  const int k0 = ks << 6;              // ks*64
  #pragma unroll 8
  for (int k = 0; k < 64; k++){
    float w = Whh[(size_t)(k0 + k)*LDG + col];
    #pragma unroll
    for (int b = 0; b < 8; b++) acc[b] = fmaf(PHl[b][k0 + k], w, acc[b]);
  }
  #pragma unroll
  for (int b = 0; b < 8; b++) red[ks][b][colq] = acc[b];
  __syncthreads();
  if (ks == 0){
    #pragma unroll
    for (int b = 0; b < 8; b++){
      float a = bf2f(Gx[(size_t)(node*8 + b)*1536 + col]);
      #pragma unroll
      for (int q = 0; q < 8; q++) a += red[q][b][colq];
      float g = sigm(a);
      G[((size_t)(t*8 + b))*1536 + col] = g;
      if (col < 512) Uf[((size_t)(t*8 + b))*512 + col] = g * PHl[b][col];
    }
  }
}

__global__ __launch_bounds__(1024)
void small_cell2(float* __restrict__ out, const ushort_t* __restrict__ Cx,
    const float* __restrict__ Wc_l, const float* __restrict__ Wc_r,
    const float* __restrict__ G, const float* __restrict__ Uf,
    const ushort_t* __restrict__ Hprev, ushort_t* __restrict__ Hcur, int s)
{
  __shared__ float Ul[8][512];         // 16KB
  __shared__ float red[8][8][128];     // 32KB
  const int t = blockIdx.x, node = s + t;
  const int tid  = threadIdx.x;
  const int colq = tid & 127;
  const int ks   = tid >> 7;
  const int col  = blockIdx.y*128 + colq;   // 0..511
  for (int idx = tid; idx < 8*512; idx += 1024){
    int b = idx >> 9, k = idx & 511;
    Ul[b][k] = Uf[((size_t)(t*8 + b))*512 + k];
  }
  __syncthreads();
  const float* Whh = (node & 1) ? Wc_l : Wc_r;
  float acc[8] = {};
  const int k0 = ks << 6;
  #pragma unroll 8
  for (int k = 0; k < 64; k++){
    float w = Whh[(size_t)(k0 + k)*HD + col];
    #pragma unroll
    for (int b = 0; b < 8; b++) acc[b] = fmaf(Ul[b][k0 + k], w, acc[b]);
  }
  #pragma unroll
  for (int b = 0; b < 8; b++) red[ks][b][colq] = acc[b];
  __syncthreads();
  if (ks == 0){
    const int prow0 = (t >> 1)*8;      // parent H base row
    #pragma unroll
    for (int b = 0; b < 8; b++){
      float a = bf2f(Cx[(size_t)(node*8 + b)*512 + col]);
      #pragma unroll
      for (int q = 0; q < 8; q++) a += red[q][b][colq];
      float zp = G[((size_t)(t*8 + b))*1536 + 512  + col];
      float zv = G[((size_t)(t*8 + b))*1536 + 1024 + col];
      float ph = bf2f(Hprev[(size_t)(prow0 + b)*512 + col]);
      float h  = zp*ph + zv*tanh_(a);
      out[((size_t)b*NNODES + (node - 1))*HD + col] = h;
      Hcur[(size_t)(t*8 + b)*512 + col] = f2bf(h);
    }
  }
}

// =======================================================================
//      FALLBACK (no ws): round-1 fused level kernel — practically unused
// =======================================================================
__device__ __forceinline__ void unpack8(uint4 u, float v[8]){
  v[0]=bf2f((unsigned short)(u.x & 0xffffu)); v[1]=bf2f((unsigned short)(u.x >> 16));
  v[2]=bf2f((unsigned short)(u.y & 0xffffu)); v[3]=bf2f((unsigned short)(u.y >> 16));
  v[4]=bf2f((unsigned short)(u.z & 0xffffu)); v[5]=bf2f((unsigned short)(u.z >> 16));
  v[6]=bf2f((unsigned short)(u.w & 0xffffu)); v[7]=bf2f((unsigned short)(u.w >> 16));
}
__device__ __forceinline__ void gemm_acc(const unsigned short* Al0,
                                         const unsigned short* Al1,
                                         const float* __restrict__ W,
                                         int ldw, int c0, float acc[2][16])
{
  const float* wr = W + c0;
  #pragma unroll 2
  for (int k0 = 0; k0 < 512; k0 += 8){
    uint4 u0 = *(const uint4*)(Al0 + k0);
    uint4 u1 = *(const uint4*)(Al1 + k0);
    float a0[8], a1[8];
    unpack8(u0, a0); unpack8(u1, a1);
    #pragma unroll
    for (int kk = 0; kk < 8; kk++){
      float wv[16];
      *(float4*)(wv+ 0) = *(const float4*)(wr+ 0);
      *(float4*)(wv+ 4) = *(const float4*)(wr+ 4);
      *(float4*)(wv+ 8) = *(const float4*)(wr+ 8);
      *(float4*)(wv+12) = *(const float4*)(wr+12);
      wr += ldw;
      float x0 = a0[kk], x1 = a1[kk];
      #pragma unroll
      for (int j = 0; j < 16; j++){
        acc[0][j] = fmaf(x0, wv[j], acc[0][j]);
        acc[1][j] = fmaf(x1, wv[j], acc[1][j]);
      }
    }
  }
}

__global__ __launch_bounds__(256)
void tdtree_level(const float* __restrict__ X, float* __restrict__ out,
    const float* __restrict__ Wg_ih, const float* __restrict__ bg,
    const float* __restrict__ Wg_l,  const float* __restrict__ Wg_r,
    const float* __restrict__ Wc_ih, const float* __restrict__ bc,
    const float* __restrict__ Wc_l,  const float* __restrict__ Wc_r,
    int s, int nodes_p, int isRoot)
{
  __shared__ __align__(16) unsigned short Xl [16][512];
  __shared__ __align__(16) unsigned short PHl[16][512];
  __shared__ __align__(16) unsigned short Ul [16][512];

  const int tid = threadIdx.x;
  const int tx  = tid & 31;
  const int ty  = tid >> 5;
  const int parity = blockIdx.y;
  const float* Wg_hh = parity ? Wg_r : Wg_l;
  const float* Wc_hh = parity ? Wc_r : Wc_l;
  const int t0 = blockIdx.x * 2;

  for (int idx = tid; idx < 16*512; idx += 256){
    int m = idx >> 9, k = idx & 511;
    int t = t0 + (m >> 3), b = m & 7;
    float xv = 0.f, pv = 0.f;
    if (t < nodes_p){
      int node = isRoot ? 0 : (s + 2*t + parity);
      xv = X[((size_t)b*NNODES + node)*ID + k];
      if (!isRoot){
        int pnode = (node - 1) >> 1;
        int pslot = pnode ? (pnode - 1) : (NNODES - 1);
        pv = out[((size_t)b*NNODES + pslot)*HD + k];
      }
    }
    Xl[m][k]  = f2bf(xv);
    PHl[m][k] = f2bf(pv);
  }
  __syncthreads();

  const int r0 = ty*2, r1 = r0 + 1;
  const int c  = tx*16;
  const unsigned short* Ax0 = &Xl[r0][0];
  const unsigned short* Ax1 = &Xl[r1][0];
  const unsigned short* Ap0 = &PHl[r0][0];
  const unsigned short* Ap1 = &PHl[r1][0];
  float acc[2][16], cell[2][16];

  #pragma unroll
  for (int j=0;j<16;j++){ float bv = bg[c+j]; acc[0][j]=bv; acc[1][j]=bv; }
  gemm_acc(Ax0, Ax1, Wg_ih, LDG, c, acc);
  if (!isRoot) gemm_acc(Ap0, Ap1, Wg_hh, LDG, c, acc);
  #pragma unroll
  for (int j=0;j<16;j++){
    Ul[r0][c+j] = f2bf(sigm(acc[0][j]) * bf2f(PHl[r0][c+j]));
    Ul[r1][c+j] = f2bf(sigm(acc[1][j]) * bf2f(PHl[r1][c+j]));
  }
  __syncthreads();

  #pragma unroll
  for (int j=0;j<16;j++){ float bv = bc[c+j]; cell[0][j]=bv; cell[1][j]=bv; }
  gemm_acc(Ax0, Ax1, Wc_ih, HD, c, cell);
  if (!isRoot) gemm_acc(&Ul[r0][0], &Ul[r1][0], Wc_hh, HD, c, cell);
  #pragma unroll
  for (int j=0;j<16;j++){ cell[0][j] = tanh_(cell[0][j]); cell[1][j] = tanh_(cell[1][j]); }

  #pragma unroll
  for (int j=0;j<16;j++){ float bv = bg[1024+c+j]; acc[0][j]=bv; acc[1][j]=bv; }
  gemm_acc(Ax0, Ax1, Wg_ih, LDG, 1024+c, acc);
  if (!isRoot) gemm_acc(Ap0, Ap1, Wg_hh, LDG, 1024+c, acc);
  #pragma unroll
  for (int j=0;j<16;j++){ cell[0][j] *= sigm(acc[0][j]); cell[1][j] *= sigm(acc[1][j]); }

  #pragma unroll
  for (int j=0;j<16;j++){ float bv = bg[512+c+j]; acc[0][j]=bv; acc[1][j]=bv; }
  gemm_acc(Ax0, Ax1, Wg_ih, LDG, 512+c, acc);
  if (!isRoot) gemm_acc(Ap0, Ap1, Wg_hh, LDG, 512+c, acc);

  #pragma unroll
  for (int i=0;i<2;i++){
    int m = r0 + i;
    int t = t0 + (m >> 3), b = m & 7;
    if (t >= nodes_p) continue;
    int node = isRoot ? 0 : (s + 2*t + parity);
    int slot = node ? (node - 1) : (NNODES - 1);
    float* op = out + ((size_t)b*NNODES + slot)*HD + c;
    float hv[16];
    if (isRoot){
      #pragma unroll
      for (int j=0;j<16;j++) hv[j] = cell[i][j];
    } else {
      int pnode = (node - 1) >> 1;
      int pslot = pnode ? (pnode - 1) : (NNODES - 1);
      const float* pp = out + ((size_t)b*NNODES + pslot)*HD + c;
      #pragma unroll
      for (int j=0;j<16;j++) hv[j] = sigm(acc[i][j]) * pp[j] + cell[i][j];
    }
    #pragma unroll
    for (int q=0;q<4;q++) *(float4*)(op + q*4) = *(const float4*)(hv + q*4);
    if (isRoot){
      float* o2 = out + (size_t)BATCH*NNODES*HD + (size_t)b*HD + c;
      #pragma unroll
      for (int q=0;q<4;q++) *(float4*)(o2 + q*4) = *(const float4*)(hv + q*4);
    }
  }
}

// =======================================================================
//                              host
// =======================================================================
extern "C" void kernel_launch(void* const* d_in, const int* in_sizes, int n_in,
                              void* d_out, int out_size, void* d_ws, size_t ws_size,
                              hipStream_t stream)
{
  const float* X     = (const float*)d_in[0];
  const float* Wg_ih = (const float*)d_in[2];
  const float* bg    = (const float*)d_in[3];
  const float* Wg_l  = (const float*)d_in[4];
  const float* Wg_r  = (const float*)d_in[5];
  const float* Wc_ih = (const float*)d_in[6];
  const float* bc    = (const float*)d_in[7];
  const float* Wc_l  = (const float*)d_in[8];
  const float* Wc_r  = (const float*)d_in[9];
  float* out = (float*)d_out;
  char* ws = (char*)d_ws;

  // ---------------- ws layout ----------------
  size_t o = 0;
  ushort_t* WgTih = (ushort_t*)(ws + o); o += (size_t)1536*512*2;
  ushort_t* WcTih = (ushort_t*)(ws + o); o += (size_t)512*512*2;
  ushort_t* WgThh = (ushort_t*)(ws + o); o += (size_t)3072*512*2;
  ushort_t* WcThh = (ushort_t*)(ws + o); o += (size_t)1024*512*2;
  ushort_t* Gxp   = (ushort_t*)(ws + o); o += (size_t)32768*1536*2;
  ushort_t* Cxp   = (ushort_t*)(ws + o); o += (size_t)32768*512*2;
  ushort_t* Hb0   = (ushort_t*)(ws + o); o += (size_t)MAXR*512*2;
  ushort_t* Hb1   = (ushort_t*)(ws + o); o += (size_t)MAXR*512*2;
  char*     BIG   = ws + o;              o += (size_t)32768*512*2;  // Abf (hoist) / Ubuf (levels)
  float*    Gs    = (float*)(ws + o);    o += (size_t)512*1536*4;   // d<=6: count*8 <= 512 rows
  float*    Us    = (float*)(ws + o);    o += (size_t)512*512*4;
  const size_t NEED = o;

  if (ws_size >= NEED){
    ushort_t* Abf  = (ushort_t*)BIG;   // [32760][512] during hoist
    ushort_t* Ubuf = (ushort_t*)BIG;   // [2][MAXR][512] during levels

    // merged: gather_X (16380 blocks) + prep_all (1152 blocks), independent
    prep_gather<<<dim3(16380 + 1152), 256, 0, stream>>>(
        X, Abf, Wg_ih, Wc_ih, Wg_l, Wg_r, Wc_l, Wc_r,
        WgTih, WcTih, WgThh, WcThh);
    gemm_hoist<<<dim3(1024), 512, 0, stream>>>(Abf, WgTih, bg, Gxp, WcTih, bc, Cxp);

    root_k<<<dim3(8), 512, 0, stream>>>(Gxp, Cxp, out, Hb0);

    for (int d = 1; d < 12; ++d){
      const int count = 1 << d, s = count - 1;
      ushort_t* Hprev = ((d-1) & 1) ? Hb1 : Hb0;
      ushort_t* Hcur  = (d & 1) ? Hb1 : Hb0;
      if (d < 7){
        small_gates2<<<dim3(count,12), 1024, 0, stream>>>(Hprev, Gxp, Wg_l, Wg_r, Gs, Us, s);
        small_cell2 <<<dim3(count,4),  1024, 0, stream>>>(out, Cxp, Wc_l, Wc_r, Gs, Us, Hprev, Hcur, s);
      } else {
        const int mt = 1 << (d - 5);     // Mp/128
        gates_rp <<<dim3(mt*8),  256, 0, stream>>>(Hprev, WgThh, Gxp, Ubuf, s);
        cell_comb<<<dim3(mt*16), 256, 0, stream>>>(Ubuf, Hprev, WcThh, WgThh,
                                                   Gxp, Cxp, out, Hcur, s, d < 11);
      }
    }
    return;
  }

  // ---------------- fallback: no-ws fused path ----------------
  for (int d = 0; d < 12; ++d){
    const int count  = 1 << d;
    const int snode  = count - 1;
    const int isRoot = (d == 0);
    const int nodes_p = isRoot ? 1 : (count >> 1);
    const int blocks  = (nodes_p + 1) >> 1;
    dim3 grid(blocks, isRoot ? 1 : 2);
    tdtree_level<<<grid, 256, 0, stream>>>(X, out, Wg_ih, bg, Wg_l, Wg_r,
                                           Wc_ih, bc, Wc_l, Wc_r,
                                           snode, nodes_p, isRoot);
  }
}

// Round 18
// 531.113 us; speedup vs baseline: 1.0700x; 1.0700x over previous
//
#include <hip/hip_runtime.h>
#include <hip/hip_bf16.h>
#include <cstdint>
#include <cstddef>

#define BATCH   8
#define NNODES  4095
#define HD      512
#define ID      512
#define LDG     1536   // gate weight leading dim (3H)
#define MAXR    8192   // max parent rows per parity (level 10 parents: 1024 x 8)

typedef unsigned short ushort_t;
typedef __attribute__((ext_vector_type(8))) short  bf16x8;
typedef __attribute__((ext_vector_type(4))) float  f32x4;

// ---------- helpers ----------
__device__ __forceinline__ float bf2f(unsigned short u){
  union { uint32_t i; float f; } v; v.i = ((uint32_t)u) << 16; return v.f;
}
__device__ __forceinline__ unsigned short f2bf(float f){
  union { float f; uint32_t i; } v; v.f = f;
  uint32_t r = v.i + 0x7fffu + ((v.i >> 16) & 1u);
  return (unsigned short)(r >> 16);
}
__device__ __forceinline__ float sigm(float x){ return 1.0f/(1.0f + __expf(-x)); }
__device__ __forceinline__ float tanh_(float x){ return 1.0f - 2.0f/(__expf(2.0f*x)+1.0f); }

// async global->LDS, 16B per lane. lds base must be wave-uniform.
#define GLOAD16(g, l) __builtin_amdgcn_global_load_lds(                      \
    (const __attribute__((address_space(1))) void*)(g),                      \
    (__attribute__((address_space(3))) void*)(l), 16, 0, 0)

// counted-vmcnt pipeline primitives (T3/T4)
#define WAIT_VM(N)  asm volatile("s_waitcnt vmcnt(" #N ")" ::: "memory")
#define WAIT_LGKM0  asm volatile("s_waitcnt lgkmcnt(0)" ::: "memory")
#define SBAR        __builtin_amdgcn_s_barrier()
#define SCHEDB      __builtin_amdgcn_sched_barrier(0)

// chunked bijective XCD swizzle (requires nwg % 8 == 0)
__device__ __forceinline__ int xcd_swz(int orig, int nwg){
  return (orig & 7) * (nwg >> 3) + (orig >> 3);
}

// ---- LDS bank swizzle for [r][32]-ushort (64B-row) staging tiles ----
// write: global_load_lds puts lane l at lds[base + (l>>2)][(l&3)*8] (linear).
// we pre-permute the GLOBAL source chunk so lds[r][s] holds chunk (s-(r&15)>>1)&3;
// read slot for chunk fq at row (..&15)=fr is  sl=(fq+(fr>>1))&3.
// PROVEN conflict-free (round-0: SQ_LDS_BANK_CONFLICT == 0).
// NOTE (round-11/15/17 lessons): counted-vmcnt across barriers requires every
// in-flight stage to target a buffer NOT read in the next window (needs 3 bufs
// on the re-read side for double-kt). Round-17: double-kt on the 512-thread
// hoist costs VGPR 96->124 and loses the 2nd co-resident block -> regression.
// The hoist stays single-kt 2-buffer (round-16 best).

// =======================================================================
// Layouts:
//  Gx  bf16[32768][1536] = X@Wg_ih + bg   (row = node*8+b)
//  Cx  bf16[32768][512]  = X@Wc_ih + bc
//  WgThh bf16[3072][512]: rows [0,1536) = Wg_l^T, [1536,3072) = Wg_r^T
//  WcThh bf16[1024][512]: rows [0,512) = Wc_l^T, [512,1024) = Wc_r^T
//  H ping-pong bf16[MAXR][512]; Ubuf bf16[2][MAXR][512]
//  Parent-row identity (all levels): node = s+t -> parent H-row = (t>>1)*8+b
// =======================================================================

// ---- merged prep (weight transpose+convert) + X gather: one dispatch ----
__global__ __launch_bounds__(256)
void prep_gather(const float* __restrict__ X, ushort_t* __restrict__ Abf,
                 const float* __restrict__ Wg_ih, const float* __restrict__ Wc_ih,
                 const float* __restrict__ Wg_l,  const float* __restrict__ Wg_r,
                 const float* __restrict__ Wc_l,  const float* __restrict__ Wc_r,
                 ushort_t* __restrict__ WgTih, ushort_t* __restrict__ WcTih,
                 ushort_t* __restrict__ WgThh, ushort_t* __restrict__ WcThh)
{
  __shared__ float t[64][65];
  const int bid = blockIdx.x;
  if (bid < 16380){
    const size_t i = (size_t)bid*256 + threadIdx.x;
    const int row = (int)(i >> 7);
    const int c4  = ((int)i & 127)*4;
    const int node = row >> 3, b = row & 7;
    float4 v = *(const float4*)&X[((size_t)b*NNODES + node)*ID + c4];
    ushort4 o = { f2bf(v.x), f2bf(v.y), f2bf(v.z), f2bf(v.w) };
    *(ushort4*)&Abf[(size_t)row*512 + c4] = o;
    return;
  }
  const int pid  = bid - 16380;          // 0..1151
  const int px   = pid % 24;
  const int py   = (pid / 24) & 7;
  const int zsel = pid / 192;            // 0..5
  const float* W; ushort_t* D; int N;
  switch (zsel){
    case 0: W = Wg_ih; D = WgTih;                        N = 1536; break;
    case 1: W = Wc_ih; D = WcTih;                        N = 512;  break;
    case 2: W = Wg_l;  D = WgThh;                        N = 1536; break;
    case 3: W = Wg_r;  D = WgThh + (size_t)1536*512;     N = 1536; break;
    case 4: W = Wc_l;  D = WcThh;                        N = 512;  break;
    default:W = Wc_r;  D = WcThh + (size_t)512*512;      N = 512;  break;
  }
  const int n0 = px*64;
  if (n0 >= N) return;
  const int k0 = py*64;
  const int c = threadIdx.x & 63, rq = threadIdx.x >> 6;
  #pragma unroll
  for (int q = 0; q < 16; ++q){
    int r = q*4 + rq;
    t[r][c] = W[(size_t)(k0 + r)*N + n0 + c];
  }
  __syncthreads();
  #pragma unroll
  for (int q = 0; q < 16; ++q){
    int r = q*4 + rq;
    D[(size_t)(n0 + r)*512 + k0 + c] = f2bf(t[c][r]);
  }
}

// ---- merged hoist GEMM: 256x256 tile, BK=32, 2-buffer counted-vmcnt ----
//  (round-16 verified best: 64KB LDS -> 2 blocks/CU, 96 VGPR, total 530.8us)
__global__ __launch_bounds__(512, 2)
void gemm_hoist(const ushort_t* __restrict__ A,
                const ushort_t* __restrict__ BTg, const float* __restrict__ bg,
                ushort_t* __restrict__ Gx,
                const ushort_t* __restrict__ BTc, const float* __restrict__ bc,
                ushort_t* __restrict__ Cx)
{
  __shared__ __align__(16) ushort_t SH[32768];   // 64KB
  ushort_t (*Al)[256][32] = (ushort_t (*)[256][32])SH;            // 2 x 16KB
  ushort_t (*Bl)[256][32] = (ushort_t (*)[256][32])(SH + 16384);  // 2 x 16KB
  const int wg = xcd_swz(blockIdx.x, gridDim.x);
  const ushort_t* BT; const float* bias; ushort_t* C; int N, m0, n0;
  if (wg < 768){ BT = BTg; bias = bg; C = Gx; N = 1536;
                 m0 = (wg/6)*256; n0 = (wg%6)*256; }
  else         { BT = BTc; bias = bc; C = Cx; N = 512;
                 const int t = wg - 768; m0 = (t>>1)*256; n0 = (t&1)*256; }
  const int tid = threadIdx.x, lane = tid & 63, wave = tid >> 6;
  const ushort_t* Abase = A + (size_t)m0*512;
  const ushort_t* Bbase = BT + (size_t)n0*512;
  const int wr = wave >> 2, wc = wave & 3;              // 2 x 4 wave grid
  const int fr = lane & 15, fq = lane >> 4;
  const int lr = lane >> 2;
  const int cs = ((lane & 3) - (lr >> 1)) & 3;          // swizzled source chunk
  const size_t lo = (size_t)lr*512 + (size_t)cs*8;      // per-lane global offset
  const int sl = (fq + (fr >> 1)) & 3;                  // swizzled read slot
  f32x4 acc[8][4] = {};

  // stage one 256x32 tile (A and B): 2+2 gloads per thread
  auto stage = [&](int buf, int kt){
    const int k0 = kt*32;
    #pragma unroll
    for (int q = 0; q < 2; ++q){
      const int r0 = (wave*2 + q)*16;      // 0..240 step 16
      GLOAD16(Abase + (size_t)r0*512 + k0 + lo, &Al[buf][r0][0]);
      GLOAD16(Bbase + (size_t)r0*512 + k0 + lo, &Bl[buf][r0][0]);
    }
  };

  stage(0, 0); stage(1, 1);
  WAIT_VM(4); SCHEDB; SBAR;            // buf0 landed; buf1 (4 gloads) in flight
  int cur = 0;
  for (int kt = 0; kt < 16; ++kt){
    bf16x8 af[8], bfr[4];
    #pragma unroll
    for (int i = 0; i < 8; i++)
      af[i] = *(const bf16x8*)&Al[cur][wr*128 + i*16 + fr][sl*8];
    #pragma unroll
    for (int j = 0; j < 4; j++)
      bfr[j] = *(const bf16x8*)&Bl[cur][wc*64 + j*16 + fr][sl*8];
    WAIT_LGKM0; SCHEDB;
    __builtin_amdgcn_s_setprio(1);
    #pragma unroll
    for (int i = 0; i < 8; i++)
      #pragma unroll
      for (int j = 0; j < 4; j++)
        acc[i][j] = __builtin_amdgcn_mfma_f32_16x16x32_bf16(af[i], bfr[j], acc[i][j], 0,0,0);
    __builtin_amdgcn_s_setprio(0);
    SCHEDB; SBAR;                      // all waves done reading cur
    if (kt < 14) stage(cur, kt + 2);   // refill just-freed buffer
    if (kt < 14) { WAIT_VM(4); } else { WAIT_VM(0); }
    SCHEDB; SBAR;                      // next buffer ready
    cur ^= 1;
  }

  // epilogue: 4 passes of 64 rows via float CT [64][256] with XOR swizzle
  float* CT = (float*)SH;
  const int er = tid >> 3;          // 0..63
  const int ec = tid & 7;           // 0..7
  #pragma unroll
  for (int p = 0; p < 4; ++p){
    __syncthreads();
    #pragma unroll
    for (int i2 = 0; i2 < 2; ++i2){
      const int i = p*2 + i2;
      #pragma unroll
      for (int j = 0; j < 4; ++j){
        const int cc = wc*64 + j*16 + fr;
        const float bv = bias[n0 + cc];
        #pragma unroll
        for (int r = 0; r < 4; ++r){
          const int crow = wr*32 + i2*16 + fq*4 + r;
          CT[crow*256 + (cc ^ ((crow & 7) << 2))] = acc[i][j][r] + bv;
        }
      }
    }
    __syncthreads();
    const int grow = m0 + p*32 + (er >> 5)*128 + (er & 31);
    ushort_t* Crow = C + (size_t)grow*N + n0;
    const int rx = (er & 7) << 2;
    #pragma unroll
    for (int q = 0; q < 8; ++q){
      const int c0 = ec*4 + q*32;
      float4 v = *(const float4*)&CT[er*256 + (c0 ^ rx)];
      ushort4 o = { f2bf(v.x), f2bf(v.y), f2bf(v.z), f2bf(v.w) };
      *(ushort4*)&Crow[c0] = o;
    }
  }
}

// ---- gates_rp: U = sigm(Hprev@Wg_hh[rp] + gx_rp) * ph ----
// double-kt: 8 iterations x {2x16 MFMA, 2 barriers}; 3-buffer rotation,
// steady-state VM(4) ledger verified (round-10: -8.6 us).
__global__ __launch_bounds__(256)
void gates_rp(const ushort_t* __restrict__ Hprev, const ushort_t* __restrict__ WgThh,
              const ushort_t* __restrict__ Gx, ushort_t* __restrict__ Ubuf, int s)
{
  __shared__ __align__(16) ushort_t Al[3][128][32];
  __shared__ __align__(16) ushort_t Bl[3][128][32];
  const int wg = xcd_swz(blockIdx.x, gridDim.x);
  const int n0 = (wg & 3)*128;
  const int z  = (wg >> 2) & 1;
  const int m0 = (wg >> 3)*128;
  const int tid = threadIdx.x, lane = tid & 63, wave = tid >> 6;
  const ushort_t* Abase = Hprev + (size_t)m0*512;
  const ushort_t* Bbase = WgThh + ((size_t)z*1536 + n0)*512;
  const int wr = wave >> 1, wc = wave & 1;
  const int fr = lane & 15, fq = lane >> 4;
  const int lr = lane >> 2;
  const int cs = ((lane & 3) - (lr >> 1)) & 3;
  const size_t lo = (size_t)lr*512 + cs*8;
  const int sl = (fq + (fr >> 1)) & 3;
  f32x4 acc[4][4] = {};

  auto stage = [&](int buf, int kt){
    const int k0 = kt*32;
    #pragma unroll
    for (int q = 0; q < 2; ++q){
      int r = q*64 + wave*16;
      GLOAD16(Abase + (size_t)r*512 + k0 + lo, &Al[buf][r][0]);
      GLOAD16(Bbase + (size_t)r*512 + k0 + lo, &Bl[buf][r][0]);
    }
  };

  stage(0, 0); stage(1, 1); stage(2, 2);
  WAIT_VM(4); SCHEDB; SBAR;          // buffers 0,1 landed; 2 in flight
  for (int it = 0; it < 8; ++it){
    const int cur = (2*it) % 3, nxt = (2*it + 1) % 3;
    bf16x8 af[4], bfr[4];
    #pragma unroll
    for (int i = 0; i < 4; i++){
      af[i]  = *(const bf16x8*)&Al[cur][wr*64 + i*16 + fr][sl*8];
      bfr[i] = *(const bf16x8*)&Bl[cur][wc*64 + i*16 + fr][sl*8];
    }
    WAIT_LGKM0; SCHEDB;
    __builtin_amdgcn_s_setprio(1);
    #pragma unroll
    for (int i = 0; i < 4; i++)
      #pragma unroll
      for (int j = 0; j < 4; j++)
        acc[i][j] = __builtin_amdgcn_mfma_f32_16x16x32_bf16(af[i], bfr[j], acc[i][j], 0,0,0);
    __builtin_amdgcn_s_setprio(0);
    #pragma unroll
    for (int i = 0; i < 4; i++){
      af[i]  = *(const bf16x8*)&Al[nxt][wr*64 + i*16 + fr][sl*8];
      bfr[i] = *(const bf16x8*)&Bl[nxt][wc*64 + i*16 + fr][sl*8];
    }
    WAIT_LGKM0; SCHEDB; SBAR;        // all waves done reading cur & nxt
    if (2*it + 3 < 16) stage(cur, 2*it + 3);
    if (2*it + 4 < 16) stage(nxt, 2*it + 4);
    __builtin_amdgcn_s_setprio(1);
    #pragma unroll
    for (int i = 0; i < 4; i++)
      #pragma unroll
      for (int j = 0; j < 4; j++)
        acc[i][j] = __builtin_amdgcn_mfma_f32_16x16x32_bf16(af[i], bfr[j], acc[i][j], 0,0,0);
    __builtin_amdgcn_s_setprio(0);
    if (2*it + 4 < 16){ WAIT_VM(4); } else { WAIT_VM(0); }
    SCHEDB; SBAR;
  }

  #pragma unroll
  for (int i = 0; i < 4; i++)
    #pragma unroll
    for (int j = 0; j < 4; j++){
      const int col = n0 + wc*64 + j*16 + fr;      // 0..511
      #pragma unroll
      for (int r = 0; r < 4; r++){
        const int m = m0 + wr*64 + i*16 + fq*4 + r;
        const int t = m >> 3, b = m & 7;
        const int node = s + 2*t + z;
        const float gx = bf2f(Gx[(size_t)(node*8 + b)*1536 + col]);
        const float ph = bf2f(Hprev[(size_t)m*512 + col]);
        Ubuf[((size_t)z*MAXR + m)*512 + col] = f2bf(sigm(acc[i][j][r] + gx) * ph);
      }
    }
}

// ---- cell_comb: fused 3-GEMM + combine, double-kt (A 3-buf, B 2-buf) ----
// (round-15 verified: -16 us)
__global__ __launch_bounds__(256)
void cell_comb(const ushort_t* __restrict__ Ubuf, const ushort_t* __restrict__ Hprev,
               const ushort_t* __restrict__ WcThh, const ushort_t* __restrict__ WgThh,
               const ushort_t* __restrict__ Gx, const ushort_t* __restrict__ Cx,
               float* __restrict__ out, ushort_t* __restrict__ Hcur,
               int s, int writeH)
{
  __shared__ __align__(16) ushort_t Ul[3][128][32];   // 24KB
  __shared__ __align__(16) ushort_t Hl[3][128][32];   // 24KB
  __shared__ __align__(16) ushort_t Bc[2][64][32];    // 8KB
  __shared__ __align__(16) ushort_t Bp[2][64][32];    // 8KB
  __shared__ __align__(16) ushort_t Bz[2][64][32];    // 8KB  (total 72KB)
  const int wg = xcd_swz(blockIdx.x, gridDim.x);
  const int n0 = (wg & 7)*64;
  const int z  = (wg >> 3) & 1;
  const int m0 = (wg >> 4)*128;
  const int tid = threadIdx.x, lane = tid & 63, wave = tid >> 6;
  const int wr = wave >> 1, wc = wave & 1;
  const int fr = lane & 15, fq = lane >> 4;
  const int lr = lane >> 2;
  const int cs = ((lane & 3) - (lr >> 1)) & 3;
  const int lc = cs*8;
  const int sl = (fq + (fr >> 1)) & 3;

  const ushort_t* Ab  = Ubuf  + ((size_t)z*MAXR + m0)*512;
  const ushort_t* Hb  = Hprev + (size_t)m0*512;
  const ushort_t* Bcb = WcThh + ((size_t)z*512  + n0)*512;
  const ushort_t* Bpb = WgThh + ((size_t)z*1536 + 512  + n0)*512;
  const ushort_t* Bzb = WgThh + ((size_t)z*1536 + 1024 + n0)*512;

  f32x4 acc_c[4][2] = {}, acc_p[4][2] = {}, acc_z[4][2] = {};

  auto stageA = [&](int buf, int kt){    // 4 gloads / thread (Ul + Hl)
    const int k0 = kt*32;
    #pragma unroll
    for (int q = 0; q < 2; ++q){
      const int r = q*64 + wave*16;
      GLOAD16(Ab + (size_t)(r + lr)*512 + k0 + lc, &Ul[buf][r][0]);
      GLOAD16(Hb + (size_t)(r + lr)*512 + k0 + lc, &Hl[buf][r][0]);
    }
  };
  auto stageB = [&](int buf, int kt){    // 3 gloads / thread (Bc,Bp,Bz)
    const int k0 = kt*32;
    const int r2 = wave*16;
    GLOAD16(Bcb + (size_t)(r2 + lr)*512 + k0 + lc, &Bc[buf][r2][0]);
    GLOAD16(Bpb + (size_t)(r2 + lr)*512 + k0 + lc, &Bp[buf][r2][0]);
    GLOAD16(Bzb + (size_t)(r2 + lr)*512 + k0 + lc, &Bz[buf][r2][0]);
  };

  auto read_frags = [&](int abuf, int bbuf, bf16x8 au[4], bf16x8 ah[4],
                        bf16x8 bc2[2], bf16x8 bp2[2], bf16x8 bz2[2]){
    #pragma unroll
    for (int i = 0; i < 4; i++){
      au[i] = *(const bf16x8*)&Ul[abuf][wr*64 + i*16 + fr][sl*8];
      ah[i] = *(const bf16x8*)&Hl[abuf][wr*64 + i*16 + fr][sl*8];
    }
    #pragma unroll
    for (int j = 0; j < 2; j++){
      bc2[j] = *(const bf16x8*)&Bc[bbuf][wc*32 + j*16 + fr][sl*8];
      bp2[j] = *(const bf16x8*)&Bp[bbuf][wc*32 + j*16 + fr][sl*8];
      bz2[j] = *(const bf16x8*)&Bz[bbuf][wc*32 + j*16 + fr][sl*8];
    }
  };

  // prologue: B first, then A, so VM(4) leaves exactly A(2) in flight
  stageB(0, 0); stageB(1, 1);
  stageA(0, 0); stageA(1, 1); stageA(2, 2);
  WAIT_VM(4); SCHEDB; SBAR;            // B(0),B(1),A(0),A(1) landed; A(2) flying

  for (int it = 0; it < 8; ++it){
    const int a0 = (2*it) % 3, a1 = (2*it + 1) % 3;
    bf16x8 au[4], ah[4], bc2[2], bp2[2], bz2[2];
    read_frags(a0, 0, au, ah, bc2, bp2, bz2);
    WAIT_LGKM0; SCHEDB;
    __builtin_amdgcn_s_setprio(1);
    #pragma unroll
    for (int i = 0; i < 4; i++)
      #pragma unroll
      for (int j = 0; j < 2; j++){
        acc_c[i][j] = __builtin_amdgcn_mfma_f32_16x16x32_bf16(au[i], bc2[j], acc_c[i][j], 0,0,0);
        acc_p[i][j] = __builtin_amdgcn_mfma_f32_16x16x32_bf16(ah[i], bp2[j], acc_p[i][j], 0,0,0);
        acc_z[i][j] = __builtin_amdgcn_mfma_f32_16x16x32_bf16(ah[i], bz2[j], acc_z[i][j], 0,0,0);
      }
    __builtin_amdgcn_s_setprio(0);
    read_frags(a1, 1, au, ah, bc2, bp2, bz2);
    WAIT_LGKM0; SCHEDB; SBAR;          // all waves done reading both halves
    if (2*it + 2 < 16) stageB(0, 2*it + 2);
    if (2*it + 3 < 16) stageB(1, 2*it + 3);
    if (2*it + 3 < 16) stageA(a0, 2*it + 3);   // (2it+3)%3 == a0
    if (2*it + 4 < 16) stageA(a1, 2*it + 4);   // (2it+4)%3 == a1
    __builtin_amdgcn_s_setprio(1);
    #pragma unroll
    for (int i = 0; i < 4; i++)
      #pragma unroll
      for (int j = 0; j < 2; j++){
        acc_c[i][j] = __builtin_amdgcn_mfma_f32_16x16x32_bf16(au[i], bc2[j], acc_c[i][j], 0,0,0);
        acc_p[i][j] = __builtin_amdgcn_mfma_f32_16x16x32_bf16(ah[i], bp2[j], acc_p[i][j], 0,0,0);
        acc_z[i][j] = __builtin_amdgcn_mfma_f32_16x16x32_bf16(ah[i], bz2[j], acc_z[i][j], 0,0,0);
      }
    __builtin_amdgcn_s_setprio(0);
    if (2*it + 4 < 16){ WAIT_VM(4); } else { WAIT_VM(0); }
    SCHEDB; SBAR;
  }

  #pragma unroll
  for (int i = 0; i < 4; i++)
    #pragma unroll
    for (int j = 0; j < 2; j++){
      const int col = n0 + wc*32 + j*16 + fr;     // 0..511
      #pragma unroll
      for (int r = 0; r < 4; r++){
        const int m = m0 + wr*64 + i*16 + fq*4 + r;
        const int t = m >> 3, b = m & 7;
        const int node = s + 2*t + z;
        const size_t crow = (size_t)node*8 + b;
        const float cell = tanh_(acc_c[i][j][r] + bf2f(Cx[crow*512 + col]));
        const float zp   = sigm(acc_p[i][j][r] + bf2f(Gx[crow*1536 + 512  + col]));
        const float zv   = sigm(acc_z[i][j][r] + bf2f(Gx[crow*1536 + 1024 + col]));
        // parent h: for node = s+2t+z, parent_local = t -> Hprev row = t*8+b = m
        const float ph = bf2f(Hprev[(size_t)m*512 + col]);
        const float h  = zp*ph + zv*cell;
        out[((size_t)b*NNODES + node - 1)*HD + col] = h;
        if (writeH) Hcur[(size_t)((2*t + z)*8 + b)*512 + col] = f2bf(h);
      }
    }
}

// ---- root: h0 = sigm(gx_z) * tanh(cx) ----
__global__ void root_k(const ushort_t* __restrict__ Gx, const ushort_t* __restrict__ Cx,
                       float* __restrict__ out, ushort_t* __restrict__ H0)
{
  const int b = blockIdx.x, c = threadIdx.x;
  float zv   = sigm(bf2f(Gx[(size_t)b*1536 + 1024 + c]));
  float cell = tanh_(bf2f(Cx[(size_t)b*512 + c]));
  float h = zv * cell;
  out[((size_t)b*NNODES + (NNODES-1))*HD + c] = h;
  out[(size_t)BATCH*NNODES*HD + (size_t)b*HD + c] = h;
  H0[(size_t)b*512 + c] = f2bf(h);
}

// ---- small levels (d=1..6): 8-way K-split, 1024-thread blocks ----
// Parent h read from Hprev (bf16, coalesced): node = s+t -> H-row (t>>1)*8+b.
__global__ __launch_bounds__(1024)
void small_gates2(const ushort_t* __restrict__ Hprev, const ushort_t* __restrict__ Gx,
    const float* __restrict__ Wg_l, const float* __restrict__ Wg_r,
    float* __restrict__ G, float* __restrict__ Uf, int s)
{
  __shared__ float PHl[8][512];        // 16KB
  __shared__ float red[8][8][128];     // 32KB: [ks][b][colq]
  const int t = blockIdx.x, node = s + t;
  const int tid  = threadIdx.x;        // 0..1023
  const int colq = tid & 127;
  const int ks   = tid >> 7;           // 0..7
  const int col  = blockIdx.y*128 + colq;   // 0..1535
  const int prow0 = (t >> 1)*8;        // parent H base row
  for (int idx = tid; idx < 8*512; idx += 1024){
    int b = idx >> 9, k = idx & 511;
    PHl[b][k] = bf2f(Hprev[(size_t)(prow0 + b)*512 + k]);
  }
  __syncthreads();
  const float* Whh = (node & 1) ? Wg_l : Wg_r;
  float acc[8] = {};
  const int k0 = ks << 6;              // ks*64
  #pragma unroll 8
  for (int k = 0; k < 64; k++){
    float w = Whh[(size_t)(k0 + k)*LDG + col];
    #pragma unroll
    for (int b = 0; b < 8; b++) acc[b] = fmaf(PHl[b][k0 + k], w, acc[b]);
  }
  #pragma unroll
  for (int b = 0; b < 8; b++) red[ks][b][colq] = acc[b];
  __syncthreads();
  if (ks == 0){
    #pragma unroll
    for (int b = 0; b < 8; b++){
      float a = bf2f(Gx[(size_t)(node*8 + b)*1536 + col]);
      #pragma unroll
      for (int q = 0; q < 8; q++) a += red[q][b][colq];
      float g = sigm(a);
      G[((size_t)(t*8 + b))*1536 + col] = g;
      if (col < 512) Uf[((size_t)(t*8 + b))*512 + col] = g * PHl[b][col];
    }
  }
}

__global__ __launch_bounds__(1024)
void small_cell2(float* __restrict__ out, const ushort_t* __restrict__ Cx,
    const float* __restrict__ Wc_l, const float* __restrict__ Wc_r,
    const float* __restrict__ G, const float* __restrict__ Uf,
    const ushort_t* __restrict__ Hprev, ushort_t* __restrict__ Hcur, int s)
{
  __shared__ float Ul[8][512];         // 16KB
  __shared__ float red[8][8][128];     // 32KB
  const int t = blockIdx.x, node = s + t;
  const int tid  = threadIdx.x;
  const int colq = tid & 127;
  const int ks   = tid >> 7;
  const int col  = blockIdx.y*128 + colq;   // 0..511
  for (int idx = tid; idx < 8*512; idx += 1024){
    int b = idx >> 9, k = idx & 511;
    Ul[b][k] = Uf[((size_t)(t*8 + b))*512 + k];
  }
  __syncthreads();
  const float* Whh = (node & 1) ? Wc_l : Wc_r;
  float acc[8] = {};
  const int k0 = ks << 6;
  #pragma unroll 8
  for (int k = 0; k < 64; k++){
    float w = Whh[(size_t)(k0 + k)*HD + col];
    #pragma unroll
    for (int b = 0; b < 8; b++) acc[b] = fmaf(Ul[b][k0 + k], w, acc[b]);
  }
  #pragma unroll
  for (int b = 0; b < 8; b++) red[ks][b][colq] = acc[b];
  __syncthreads();
  if (ks == 0){
    const int prow0 = (t >> 1)*8;      // parent H base row
    #pragma unroll
    for (int b = 0; b < 8; b++){
      float a = bf2f(Cx[(size_t)(node*8 + b)*512 + col]);
      #pragma unroll
      for (int q = 0; q < 8; q++) a += red[q][b][colq];
      float zp = G[((size_t)(t*8 + b))*1536 + 512  + col];
      float zv = G[((size_t)(t*8 + b))*1536 + 1024 + col];
      float ph = bf2f(Hprev[(size_t)(prow0 + b)*512 + col]);
      float h  = zp*ph + zv*tanh_(a);
      out[((size_t)b*NNODES + (node - 1))*HD + col] = h;
      Hcur[(size_t)(t*8 + b)*512 + col] = f2bf(h);
    }
  }
}

// =======================================================================
//      FALLBACK (no ws): round-1 fused level kernel — practically unused
// =======================================================================
__device__ __forceinline__ void unpack8(uint4 u, float v[8]){
  v[0]=bf2f((unsigned short)(u.x & 0xffffu)); v[1]=bf2f((unsigned short)(u.x >> 16));
  v[2]=bf2f((unsigned short)(u.y & 0xffffu)); v[3]=bf2f((unsigned short)(u.y >> 16));
  v[4]=bf2f((unsigned short)(u.z & 0xffffu)); v[5]=bf2f((unsigned short)(u.z >> 16));
  v[6]=bf2f((unsigned short)(u.w & 0xffffu)); v[7]=bf2f((unsigned short)(u.w >> 16));
}
__device__ __forceinline__ void gemm_acc(const unsigned short* Al0,
                                         const unsigned short* Al1,
                                         const float* __restrict__ W,
                                         int ldw, int c0, float acc[2][16])
{
  const float* wr = W + c0;
  #pragma unroll 2
  for (int k0 = 0; k0 < 512; k0 += 8){
    uint4 u0 = *(const uint4*)(Al0 + k0);
    uint4 u1 = *(const uint4*)(Al1 + k0);
    float a0[8], a1[8];
    unpack8(u0, a0); unpack8(u1, a1);
    #pragma unroll
    for (int kk = 0; kk < 8; kk++){
      float wv[16];
      *(float4*)(wv+ 0) = *(const float4*)(wr+ 0);
      *(float4*)(wv+ 4) = *(const float4*)(wr+ 4);
      *(float4*)(wv+ 8) = *(const float4*)(wr+ 8);
      *(float4*)(wv+12) = *(const float4*)(wr+12);
      wr += ldw;
      float x0 = a0[kk], x1 = a1[kk];
      #pragma unroll
      for (int j = 0; j < 16; j++){
        acc[0][j] = fmaf(x0, wv[j], acc[0][j]);
        acc[1][j] = fmaf(x1, wv[j], acc[1][j]);
      }
    }
  }
}

__global__ __launch_bounds__(256)
void tdtree_level(const float* __restrict__ X, float* __restrict__ out,
    const float* __restrict__ Wg_ih, const float* __restrict__ bg,
    const float* __restrict__ Wg_l,  const float* __restrict__ Wg_r,
    const float* __restrict__ Wc_ih, const float* __restrict__ bc,
    const float* __restrict__ Wc_l,  const float* __restrict__ Wc_r,
    int s, int nodes_p, int isRoot)
{
  __shared__ __align__(16) unsigned short Xl [16][512];
  __shared__ __align__(16) unsigned short PHl[16][512];
  __shared__ __align__(16) unsigned short Ul [16][512];

  const int tid = threadIdx.x;
  const int tx  = tid & 31;
  const int ty  = tid >> 5;
  const int parity = blockIdx.y;
  const float* Wg_hh = parity ? Wg_r : Wg_l;
  const float* Wc_hh = parity ? Wc_r : Wc_l;
  const int t0 = blockIdx.x * 2;

  for (int idx = tid; idx < 16*512; idx += 256){
    int m = idx >> 9, k = idx & 511;
    int t = t0 + (m >> 3), b = m & 7;
    float xv = 0.f, pv = 0.f;
    if (t < nodes_p){
      int node = isRoot ? 0 : (s + 2*t + parity);
      xv = X[((size_t)b*NNODES + node)*ID + k];
      if (!isRoot){
        int pnode = (node - 1) >> 1;
        int pslot = pnode ? (pnode - 1) : (NNODES - 1);
        pv = out[((size_t)b*NNODES + pslot)*HD + k];
      }
    }
    Xl[m][k]  = f2bf(xv);
    PHl[m][k] = f2bf(pv);
  }
  __syncthreads();

  const int r0 = ty*2, r1 = r0 + 1;
  const int c  = tx*16;
  const unsigned short* Ax0 = &Xl[r0][0];
  const unsigned short* Ax1 = &Xl[r1][0];
  const unsigned short* Ap0 = &PHl[r0][0];
  const unsigned short* Ap1 = &PHl[r1][0];
  float acc[2][16], cell[2][16];

  #pragma unroll
  for (int j=0;j<16;j++){ float bv = bg[c+j]; acc[0][j]=bv; acc[1][j]=bv; }
  gemm_acc(Ax0, Ax1, Wg_ih, LDG, c, acc);
  if (!isRoot) gemm_acc(Ap0, Ap1, Wg_hh, LDG, c, acc);
  #pragma unroll
  for (int j=0;j<16;j++){
    Ul[r0][c+j] = f2bf(sigm(acc[0][j]) * bf2f(PHl[r0][c+j]));
    Ul[r1][c+j] = f2bf(sigm(acc[1][j]) * bf2f(PHl[r1][c+j]));
  }
  __syncthreads();

  #pragma unroll
  for (int j=0;j<16;j++){ float bv = bc[c+j]; cell[0][j]=bv; cell[1][j]=bv; }
  gemm_acc(Ax0, Ax1, Wc_ih, HD, c, cell);
  if (!isRoot) gemm_acc(&Ul[r0][0], &Ul[r1][0], Wc_hh, HD, c, cell);
  #pragma unroll
  for (int j=0;j<16;j++){ cell[0][j] = tanh_(cell[0][j]); cell[1][j] = tanh_(cell[1][j]); }

  #pragma unroll
  for (int j=0;j<16;j++){ float bv = bg[1024+c+j]; acc[0][j]=bv; acc[1][j]=bv; }
  gemm_acc(Ax0, Ax1, Wg_ih, LDG, 1024+c, acc);
  if (!isRoot) gemm_acc(Ap0, Ap1, Wg_hh, LDG, 1024+c, acc);
  #pragma unroll
  for (int j=0;j<16;j++){ cell[0][j] *= sigm(acc[0][j]); cell[1][j] *= sigm(acc[1][j]); }

  #pragma unroll
  for (int j=0;j<16;j++){ float bv = bg[512+c+j]; acc[0][j]=bv; acc[1][j]=bv; }
  gemm_acc(Ax0, Ax1, Wg_ih, LDG, 512+c, acc);
  if (!isRoot) gemm_acc(Ap0, Ap1, Wg_hh, LDG, 512+c, acc);

  #pragma unroll
  for (int i=0;i<2;i++){
    int m = r0 + i;
    int t = t0 + (m >> 3), b = m & 7;
    if (t >= nodes_p) continue;
    int node = isRoot ? 0 : (s + 2*t + parity);
    int slot = node ? (node - 1) : (NNODES - 1);
    float* op = out + ((size_t)b*NNODES + slot)*HD + c;
    float hv[16];
    if (isRoot){
      #pragma unroll
      for (int j=0;j<16;j++) hv[j] = cell[i][j];
    } else {
      int pnode = (node - 1) >> 1;
      int pslot = pnode ? (pnode - 1) : (NNODES - 1);
      const float* pp = out + ((size_t)b*NNODES + pslot)*HD + c;
      #pragma unroll
      for (int j=0;j<16;j++) hv[j] = sigm(acc[i][j]) * pp[j] + cell[i][j];
    }
    #pragma unroll
    for (int q=0;q<4;q++) *(float4*)(op + q*4) = *(const float4*)(hv + q*4);
    if (isRoot){
      float* o2 = out + (size_t)BATCH*NNODES*HD + (size_t)b*HD + c;
      #pragma unroll
      for (int q=0;q<4;q++) *(float4*)(o2 + q*4) = *(const float4*)(hv + q*4);
    }
  }
}

// =======================================================================
//                              host
// =======================================================================
extern "C" void kernel_launch(void* const* d_in, const int* in_sizes, int n_in,
                              void* d_out, int out_size, void* d_ws, size_t ws_size,
                              hipStream_t stream)
{
  const float* X     = (const float*)d_in[0];
  const float* Wg_ih = (const float*)d_in[2];
  const float* bg    = (const float*)d_in[3];
  const float* Wg_l  = (const float*)d_in[4];
  const float* Wg_r  = (const float*)d_in[5];
  const float* Wc_ih = (const float*)d_in[6];
  const float* bc    = (const float*)d_in[7];
  const float* Wc_l  = (const float*)d_in[8];
  const float* Wc_r  = (const float*)d_in[9];
  float* out = (float*)d_out;
  char* ws = (char*)d_ws;

  // ---------------- ws layout ----------------
  size_t o = 0;
  ushort_t* WgTih = (ushort_t*)(ws + o); o += (size_t)1536*512*2;
  ushort_t* WcTih = (ushort_t*)(ws + o); o += (size_t)512*512*2;
  ushort_t* WgThh = (ushort_t*)(ws + o); o += (size_t)3072*512*2;
  ushort_t* WcThh = (ushort_t*)(ws + o); o += (size_t)1024*512*2;
  ushort_t* Gxp   = (ushort_t*)(ws + o); o += (size_t)32768*1536*2;
  ushort_t* Cxp   = (ushort_t*)(ws + o); o += (size_t)32768*512*2;
  ushort_t* Hb0   = (ushort_t*)(ws + o); o += (size_t)MAXR*512*2;
  ushort_t* Hb1   = (ushort_t*)(ws + o); o += (size_t)MAXR*512*2;
  char*     BIG   = ws + o;              o += (size_t)32768*512*2;  // Abf (hoist) / Ubuf (levels)
  float*    Gs    = (float*)(ws + o);    o += (size_t)512*1536*4;   // d<=6: count*8 <= 512 rows
  float*    Us    = (float*)(ws + o);    o += (size_t)512*512*4;
  const size_t NEED = o;

  if (ws_size >= NEED){
    ushort_t* Abf  = (ushort_t*)BIG;   // [32760][512] during hoist
    ushort_t* Ubuf = (ushort_t*)BIG;   // [2][MAXR][512] during levels

    // merged: gather_X (16380 blocks) + prep_all (1152 blocks), independent
    prep_gather<<<dim3(16380 + 1152), 256, 0, stream>>>(
        X, Abf, Wg_ih, Wc_ih, Wg_l, Wg_r, Wc_l, Wc_r,
        WgTih, WcTih, WgThh, WcThh);
    gemm_hoist<<<dim3(1024), 512, 0, stream>>>(Abf, WgTih, bg, Gxp, WcTih, bc, Cxp);

    root_k<<<dim3(8), 512, 0, stream>>>(Gxp, Cxp, out, Hb0);

    for (int d = 1; d < 12; ++d){
      const int count = 1 << d, s = count - 1;
      ushort_t* Hprev = ((d-1) & 1) ? Hb1 : Hb0;
      ushort_t* Hcur  = (d & 1) ? Hb1 : Hb0;
      if (d < 7){
        small_gates2<<<dim3(count,12), 1024, 0, stream>>>(Hprev, Gxp, Wg_l, Wg_r, Gs, Us, s);
        small_cell2 <<<dim3(count,4),  1024, 0, stream>>>(out, Cxp, Wc_l, Wc_r, Gs, Us, Hprev, Hcur, s);
      } else {
        const int mt = 1 << (d - 5);     // Mp/128
        gates_rp <<<dim3(mt*8),  256, 0, stream>>>(Hprev, WgThh, Gxp, Ubuf, s);
        cell_comb<<<dim3(mt*16), 256, 0, stream>>>(Ubuf, Hprev, WcThh, WgThh,
                                                   Gxp, Cxp, out, Hcur, s, d < 11);
      }
    }
    return;
  }

  // ---------------- fallback: no-ws fused path ----------------
  for (int d = 0; d < 12; ++d){
    const int count  = 1 << d;
    const int snode  = count - 1;
    const int isRoot = (d == 0);
    const int nodes_p = isRoot ? 1 : (count >> 1);
    const int blocks  = (nodes_p + 1) >> 1;
    dim3 grid(blocks, isRoot ? 1 : 2);
    tdtree_level<<<grid, 256, 0, stream>>>(X, out, Wg_ih, bg, Wg_l, Wg_r,
                                           Wc_ih, bc, Wc_l, Wc_r,
                                           snode, nodes_p, isRoot);
  }
}

// Round 19
// 529.634 us; speedup vs baseline: 1.0730x; 1.0028x over previous
//
#include <hip/hip_runtime.h>
#include <hip/hip_bf16.h>
#include <cstdint>
#include <cstddef>

#define BATCH   8
#define NNODES  4095
#define HD      512
#define ID      512
#define LDG     1536   // gate weight leading dim (3H)
#define MAXR    8192   // max parent rows per parity (level 10 parents: 1024 x 8)

typedef unsigned short ushort_t;
typedef __attribute__((ext_vector_type(8))) short  bf16x8;
typedef __attribute__((ext_vector_type(4))) float  f32x4;

// ---------- helpers ----------
__device__ __forceinline__ float bf2f(unsigned short u){
  union { uint32_t i; float f; } v; v.i = ((uint32_t)u) << 16; return v.f;
}
__device__ __forceinline__ unsigned short f2bf(float f){
  union { float f; uint32_t i; } v; v.f = f;
  uint32_t r = v.i + 0x7fffu + ((v.i >> 16) & 1u);
  return (unsigned short)(r >> 16);
}
__device__ __forceinline__ float sigm(float x){ return 1.0f/(1.0f + __expf(-x)); }
__device__ __forceinline__ float tanh_(float x){ return 1.0f - 2.0f/(__expf(2.0f*x)+1.0f); }

// async global->LDS, 16B per lane. lds base must be wave-uniform.
#define GLOAD16(g, l) __builtin_amdgcn_global_load_lds(                      \
    (const __attribute__((address_space(1))) void*)(g),                      \
    (__attribute__((address_space(3))) void*)(l), 16, 0, 0)

// counted-vmcnt pipeline primitives (T3/T4)
#define WAIT_VM(N)  asm volatile("s_waitcnt vmcnt(" #N ")" ::: "memory")
#define WAIT_LGKM0  asm volatile("s_waitcnt lgkmcnt(0)" ::: "memory")
#define SBAR        __builtin_amdgcn_s_barrier()
#define SCHEDB      __builtin_amdgcn_sched_barrier(0)

// chunked bijective XCD swizzle (requires nwg % 8 == 0)
__device__ __forceinline__ int xcd_swz(int orig, int nwg){
  return (orig & 7) * (nwg >> 3) + (orig >> 3);
}

// ---- LDS bank swizzle for [r][32]-ushort (64B-row) staging tiles ----
// write: global_load_lds puts lane l at lds[base + (l>>2)][(l&3)*8] (linear).
// we pre-permute the GLOBAL source chunk so lds[r][s] holds chunk (s-(r&15)>>1)&3;
// read slot for chunk fq at row (..&15)=fr is  sl=(fq+(fr>>1))&3.
// PROVEN conflict-free (round-0: SQ_LDS_BANK_CONFLICT == 0).
// NOTE (round-11/15/17 lessons): counted-vmcnt across barriers requires every
// in-flight stage to target a buffer NOT read in the next window (needs 3 bufs
// on the re-read side for double-kt). Round-17: double-kt on the 512-thread
// hoist costs VGPR 96->124 and loses the 2nd co-resident block -> regression.
// The hoist stays single-kt 2-buffer (round-16 best).

// =======================================================================
// Layouts:
//  Gx  bf16[32768][1536] = X@Wg_ih + bg   (row = node*8+b)
//  Cx  bf16[32768][512]  = X@Wc_ih + bc
//  WgThh bf16[3072][512]: rows [0,1536) = Wg_l^T, [1536,3072) = Wg_r^T
//  WcThh bf16[1024][512]: rows [0,512) = Wc_l^T, [512,1024) = Wc_r^T
//  H ping-pong bf16[MAXR][512]; Ubuf bf16[2][MAXR][512]
//  Parent-row identity (all levels): node = s+t -> parent H-row = (t>>1)*8+b
// =======================================================================

// ---- merged prep (weight transpose+convert) + X gather: one dispatch ----
__global__ __launch_bounds__(256)
void prep_gather(const float* __restrict__ X, ushort_t* __restrict__ Abf,
                 const float* __restrict__ Wg_ih, const float* __restrict__ Wc_ih,
                 const float* __restrict__ Wg_l,  const float* __restrict__ Wg_r,
                 const float* __restrict__ Wc_l,  const float* __restrict__ Wc_r,
                 ushort_t* __restrict__ WgTih, ushort_t* __restrict__ WcTih,
                 ushort_t* __restrict__ WgThh, ushort_t* __restrict__ WcThh)
{
  __shared__ float t[64][65];
  const int bid = blockIdx.x;
  if (bid < 16380){
    const size_t i = (size_t)bid*256 + threadIdx.x;
    const int row = (int)(i >> 7);
    const int c4  = ((int)i & 127)*4;
    const int node = row >> 3, b = row & 7;
    float4 v = *(const float4*)&X[((size_t)b*NNODES + node)*ID + c4];
    ushort4 o = { f2bf(v.x), f2bf(v.y), f2bf(v.z), f2bf(v.w) };
    *(ushort4*)&Abf[(size_t)row*512 + c4] = o;
    return;
  }
  const int pid  = bid - 16380;          // 0..1151
  const int px   = pid % 24;
  const int py   = (pid / 24) & 7;
  const int zsel = pid / 192;            // 0..5
  const float* W; ushort_t* D; int N;
  switch (zsel){
    case 0: W = Wg_ih; D = WgTih;                        N = 1536; break;
    case 1: W = Wc_ih; D = WcTih;                        N = 512;  break;
    case 2: W = Wg_l;  D = WgThh;                        N = 1536; break;
    case 3: W = Wg_r;  D = WgThh + (size_t)1536*512;     N = 1536; break;
    case 4: W = Wc_l;  D = WcThh;                        N = 512;  break;
    default:W = Wc_r;  D = WcThh + (size_t)512*512;      N = 512;  break;
  }
  const int n0 = px*64;
  if (n0 >= N) return;
  const int k0 = py*64;
  const int c = threadIdx.x & 63, rq = threadIdx.x >> 6;
  #pragma unroll
  for (int q = 0; q < 16; ++q){
    int r = q*4 + rq;
    t[r][c] = W[(size_t)(k0 + r)*N + n0 + c];
  }
  __syncthreads();
  #pragma unroll
  for (int q = 0; q < 16; ++q){
    int r = q*4 + rq;
    D[(size_t)(n0 + r)*512 + k0 + c] = f2bf(t[c][r]);
  }
}

// ---- merged hoist GEMM: 256x256 tile, BK=32, 2-buffer counted-vmcnt ----
//  (round-16 verified best: 64KB LDS -> 2 blocks/CU, 96 VGPR)
//  Round-19: m0-major tile decode — all 8 N-tiles (6 Gx + 2 Cx) of one
//  A-panel are wg-contiguous -> same XCD chunk -> A fetched into one L2.
__global__ __launch_bounds__(512, 2)
void gemm_hoist(const ushort_t* __restrict__ A,
                const ushort_t* __restrict__ BTg, const float* __restrict__ bg,
                ushort_t* __restrict__ Gx,
                const ushort_t* __restrict__ BTc, const float* __restrict__ bc,
                ushort_t* __restrict__ Cx)
{
  __shared__ __align__(16) ushort_t SH[32768];   // 64KB
  ushort_t (*Al)[256][32] = (ushort_t (*)[256][32])SH;            // 2 x 16KB
  ushort_t (*Bl)[256][32] = (ushort_t (*)[256][32])(SH + 16384);  // 2 x 16KB
  const int wg = xcd_swz(blockIdx.x, gridDim.x);
  const int mt = wg >> 3, rsel = wg & 7;          // m0-major: 8 tiles per panel
  const ushort_t* BT; const float* bias; ushort_t* C; int N, m0, n0;
  if (rsel < 6){ BT = BTg; bias = bg; C = Gx; N = 1536;
                 m0 = mt*256; n0 = rsel*256; }
  else         { BT = BTc; bias = bc; C = Cx; N = 512;
                 m0 = mt*256; n0 = (rsel - 6)*256; }
  const int tid = threadIdx.x, lane = tid & 63, wave = tid >> 6;
  const ushort_t* Abase = A + (size_t)m0*512;
  const ushort_t* Bbase = BT + (size_t)n0*512;
  const int wr = wave >> 2, wc = wave & 3;              // 2 x 4 wave grid
  const int fr = lane & 15, fq = lane >> 4;
  const int lr = lane >> 2;
  const int cs = ((lane & 3) - (lr >> 1)) & 3;          // swizzled source chunk
  const size_t lo = (size_t)lr*512 + (size_t)cs*8;      // per-lane global offset
  const int sl = (fq + (fr >> 1)) & 3;                  // swizzled read slot
  f32x4 acc[8][4] = {};

  // stage one 256x32 tile (A and B): 2+2 gloads per thread
  auto stage = [&](int buf, int kt){
    const int k0 = kt*32;
    #pragma unroll
    for (int q = 0; q < 2; ++q){
      const int r0 = (wave*2 + q)*16;      // 0..240 step 16
      GLOAD16(Abase + (size_t)r0*512 + k0 + lo, &Al[buf][r0][0]);
      GLOAD16(Bbase + (size_t)r0*512 + k0 + lo, &Bl[buf][r0][0]);
    }
  };

  stage(0, 0); stage(1, 1);
  WAIT_VM(4); SCHEDB; SBAR;            // buf0 landed; buf1 (4 gloads) in flight
  int cur = 0;
  for (int kt = 0; kt < 16; ++kt){
    bf16x8 af[8], bfr[4];
    #pragma unroll
    for (int i = 0; i < 8; i++)
      af[i] = *(const bf16x8*)&Al[cur][wr*128 + i*16 + fr][sl*8];
    #pragma unroll
    for (int j = 0; j < 4; j++)
      bfr[j] = *(const bf16x8*)&Bl[cur][wc*64 + j*16 + fr][sl*8];
    WAIT_LGKM0; SCHEDB;
    __builtin_amdgcn_s_setprio(1);
    #pragma unroll
    for (int i = 0; i < 8; i++)
      #pragma unroll
      for (int j = 0; j < 4; j++)
        acc[i][j] = __builtin_amdgcn_mfma_f32_16x16x32_bf16(af[i], bfr[j], acc[i][j], 0,0,0);
    __builtin_amdgcn_s_setprio(0);
    SCHEDB; SBAR;                      // all waves done reading cur
    if (kt < 14) stage(cur, kt + 2);   // refill just-freed buffer
    if (kt < 14) { WAIT_VM(4); } else { WAIT_VM(0); }
    SCHEDB; SBAR;                      // next buffer ready
    cur ^= 1;
  }

  // epilogue: 4 passes of 64 rows via float CT [64][256] with XOR swizzle
  float* CT = (float*)SH;
  const int er = tid >> 3;          // 0..63
  const int ec = tid & 7;           // 0..7
  #pragma unroll
  for (int p = 0; p < 4; ++p){
    __syncthreads();
    #pragma unroll
    for (int i2 = 0; i2 < 2; ++i2){
      const int i = p*2 + i2;
      #pragma unroll
      for (int j = 0; j < 4; ++j){
        const int cc = wc*64 + j*16 + fr;
        const float bv = bias[n0 + cc];
        #pragma unroll
        for (int r = 0; r < 4; ++r){
          const int crow = wr*32 + i2*16 + fq*4 + r;
          CT[crow*256 + (cc ^ ((crow & 7) << 2))] = acc[i][j][r] + bv;
        }
      }
    }
    __syncthreads();
    const int grow = m0 + p*32 + (er >> 5)*128 + (er & 31);
    ushort_t* Crow = C + (size_t)grow*N + n0;
    const int rx = (er & 7) << 2;
    #pragma unroll
    for (int q = 0; q < 8; ++q){
      const int c0 = ec*4 + q*32;
      float4 v = *(const float4*)&CT[er*256 + (c0 ^ rx)];
      ushort4 o = { f2bf(v.x), f2bf(v.y), f2bf(v.z), f2bf(v.w) };
      *(ushort4*)&Crow[c0] = o;
    }
  }
}

// ---- gates_rp: U = sigm(Hprev@Wg_hh[rp] + gx_rp) * ph ----
// double-kt: 8 iterations x {2x16 MFMA, 2 barriers}; 3-buffer rotation,
// steady-state VM(4) ledger verified (round-10: -8.6 us).
__global__ __launch_bounds__(256)
void gates_rp(const ushort_t* __restrict__ Hprev, const ushort_t* __restrict__ WgThh,
              const ushort_t* __restrict__ Gx, ushort_t* __restrict__ Ubuf, int s)
{
  __shared__ __align__(16) ushort_t Al[3][128][32];
  __shared__ __align__(16) ushort_t Bl[3][128][32];
  const int wg = xcd_swz(blockIdx.x, gridDim.x);
  const int n0 = (wg & 3)*128;
  const int z  = (wg >> 2) & 1;
  const int m0 = (wg >> 3)*128;
  const int tid = threadIdx.x, lane = tid & 63, wave = tid >> 6;
  const ushort_t* Abase = Hprev + (size_t)m0*512;
  const ushort_t* Bbase = WgThh + ((size_t)z*1536 + n0)*512;
  const int wr = wave >> 1, wc = wave & 1;
  const int fr = lane & 15, fq = lane >> 4;
  const int lr = lane >> 2;
  const int cs = ((lane & 3) - (lr >> 1)) & 3;
  const size_t lo = (size_t)lr*512 + cs*8;
  const int sl = (fq + (fr >> 1)) & 3;
  f32x4 acc[4][4] = {};

  auto stage = [&](int buf, int kt){
    const int k0 = kt*32;
    #pragma unroll
    for (int q = 0; q < 2; ++q){
      int r = q*64 + wave*16;
      GLOAD16(Abase + (size_t)r*512 + k0 + lo, &Al[buf][r][0]);
      GLOAD16(Bbase + (size_t)r*512 + k0 + lo, &Bl[buf][r][0]);
    }
  };

  stage(0, 0); stage(1, 1); stage(2, 2);
  WAIT_VM(4); SCHEDB; SBAR;          // buffers 0,1 landed; 2 in flight
  for (int it = 0; it < 8; ++it){
    const int cur = (2*it) % 3, nxt = (2*it + 1) % 3;
    bf16x8 af[4], bfr[4];
    #pragma unroll
    for (int i = 0; i < 4; i++){
      af[i]  = *(const bf16x8*)&Al[cur][wr*64 + i*16 + fr][sl*8];
      bfr[i] = *(const bf16x8*)&Bl[cur][wc*64 + i*16 + fr][sl*8];
    }
    WAIT_LGKM0; SCHEDB;
    __builtin_amdgcn_s_setprio(1);
    #pragma unroll
    for (int i = 0; i < 4; i++)
      #pragma unroll
      for (int j = 0; j < 4; j++)
        acc[i][j] = __builtin_amdgcn_mfma_f32_16x16x32_bf16(af[i], bfr[j], acc[i][j], 0,0,0);
    __builtin_amdgcn_s_setprio(0);
    #pragma unroll
    for (int i = 0; i < 4; i++){
      af[i]  = *(const bf16x8*)&Al[nxt][wr*64 + i*16 + fr][sl*8];
      bfr[i] = *(const bf16x8*)&Bl[nxt][wc*64 + i*16 + fr][sl*8];
    }
    WAIT_LGKM0; SCHEDB; SBAR;        // all waves done reading cur & nxt
    if (2*it + 3 < 16) stage(cur, 2*it + 3);
    if (2*it + 4 < 16) stage(nxt, 2*it + 4);
    __builtin_amdgcn_s_setprio(1);
    #pragma unroll
    for (int i = 0; i < 4; i++)
      #pragma unroll
      for (int j = 0; j < 4; j++)
        acc[i][j] = __builtin_amdgcn_mfma_f32_16x16x32_bf16(af[i], bfr[j], acc[i][j], 0,0,0);
    __builtin_amdgcn_s_setprio(0);
    if (2*it + 4 < 16){ WAIT_VM(4); } else { WAIT_VM(0); }
    SCHEDB; SBAR;
  }

  #pragma unroll
  for (int i = 0; i < 4; i++)
    #pragma unroll
    for (int j = 0; j < 4; j++){
      const int col = n0 + wc*64 + j*16 + fr;      // 0..511
      #pragma unroll
      for (int r = 0; r < 4; r++){
        const int m = m0 + wr*64 + i*16 + fq*4 + r;
        const int t = m >> 3, b = m & 7;
        const int node = s + 2*t + z;
        const float gx = bf2f(Gx[(size_t)(node*8 + b)*1536 + col]);
        const float ph = bf2f(Hprev[(size_t)m*512 + col]);
        Ubuf[((size_t)z*MAXR + m)*512 + col] = f2bf(sigm(acc[i][j][r] + gx) * ph);
      }
    }
}

// ---- cell_comb: fused 3-GEMM + combine, double-kt (A 3-buf, B 2-buf) ----
// (round-15 verified: -16 us)
__global__ __launch_bounds__(256)
void cell_comb(const ushort_t* __restrict__ Ubuf, const ushort_t* __restrict__ Hprev,
               const ushort_t* __restrict__ WcThh, const ushort_t* __restrict__ WgThh,
               const ushort_t* __restrict__ Gx, const ushort_t* __restrict__ Cx,
               float* __restrict__ out, ushort_t* __restrict__ Hcur,
               int s, int writeH)
{
  __shared__ __align__(16) ushort_t Ul[3][128][32];   // 24KB
  __shared__ __align__(16) ushort_t Hl[3][128][32];   // 24KB
  __shared__ __align__(16) ushort_t Bc[2][64][32];    // 8KB
  __shared__ __align__(16) ushort_t Bp[2][64][32];    // 8KB
  __shared__ __align__(16) ushort_t Bz[2][64][32];    // 8KB  (total 72KB)
  const int wg = xcd_swz(blockIdx.x, gridDim.x);
  const int n0 = (wg & 7)*64;
  const int z  = (wg >> 3) & 1;
  const int m0 = (wg >> 4)*128;
  const int tid = threadIdx.x, lane = tid & 63, wave = tid >> 6;
  const int wr = wave >> 1, wc = wave & 1;
  const int fr = lane & 15, fq = lane >> 4;
  const int lr = lane >> 2;
  const int cs = ((lane & 3) - (lr >> 1)) & 3;
  const int lc = cs*8;
  const int sl = (fq + (fr >> 1)) & 3;

  const ushort_t* Ab  = Ubuf  + ((size_t)z*MAXR + m0)*512;
  const ushort_t* Hb  = Hprev + (size_t)m0*512;
  const ushort_t* Bcb = WcThh + ((size_t)z*512  + n0)*512;
  const ushort_t* Bpb = WgThh + ((size_t)z*1536 + 512  + n0)*512;
  const ushort_t* Bzb = WgThh + ((size_t)z*1536 + 1024 + n0)*512;

  f32x4 acc_c[4][2] = {}, acc_p[4][2] = {}, acc_z[4][2] = {};

  auto stageA = [&](int buf, int kt){    // 4 gloads / thread (Ul + Hl)
    const int k0 = kt*32;
    #pragma unroll
    for (int q = 0; q < 2; ++q){
      const int r = q*64 + wave*16;
      GLOAD16(Ab + (size_t)(r + lr)*512 + k0 + lc, &Ul[buf][r][0]);
      GLOAD16(Hb + (size_t)(r + lr)*512 + k0 + lc, &Hl[buf][r][0]);
    }
  };
  auto stageB = [&](int buf, int kt){    // 3 gloads / thread (Bc,Bp,Bz)
    const int k0 = kt*32;
    const int r2 = wave*16;
    GLOAD16(Bcb + (size_t)(r2 + lr)*512 + k0 + lc, &Bc[buf][r2][0]);
    GLOAD16(Bpb + (size_t)(r2 + lr)*512 + k0 + lc, &Bp[buf][r2][0]);
    GLOAD16(Bzb + (size_t)(r2 + lr)*512 + k0 + lc, &Bz[buf][r2][0]);
  };

  auto read_frags = [&](int abuf, int bbuf, bf16x8 au[4], bf16x8 ah[4],
                        bf16x8 bc2[2], bf16x8 bp2[2], bf16x8 bz2[2]){
    #pragma unroll
    for (int i = 0; i < 4; i++){
      au[i] = *(const bf16x8*)&Ul[abuf][wr*64 + i*16 + fr][sl*8];
      ah[i] = *(const bf16x8*)&Hl[abuf][wr*64 + i*16 + fr][sl*8];
    }
    #pragma unroll
    for (int j = 0; j < 2; j++){
      bc2[j] = *(const bf16x8*)&Bc[bbuf][wc*32 + j*16 + fr][sl*8];
      bp2[j] = *(const bf16x8*)&Bp[bbuf][wc*32 + j*16 + fr][sl*8];
      bz2[j] = *(const bf16x8*)&Bz[bbuf][wc*32 + j*16 + fr][sl*8];
    }
  };

  // prologue: B first, then A, so VM(4) leaves exactly A(2) in flight
  stageB(0, 0); stageB(1, 1);
  stageA(0, 0); stageA(1, 1); stageA(2, 2);
  WAIT_VM(4); SCHEDB; SBAR;            // B(0),B(1),A(0),A(1) landed; A(2) flying

  for (int it = 0; it < 8; ++it){
    const int a0 = (2*it) % 3, a1 = (2*it + 1) % 3;
    bf16x8 au[4], ah[4], bc2[2], bp2[2], bz2[2];
    read_frags(a0, 0, au, ah, bc2, bp2, bz2);
    WAIT_LGKM0; SCHEDB;
    __builtin_amdgcn_s_setprio(1);
    #pragma unroll
    for (int i = 0; i < 4; i++)
      #pragma unroll
      for (int j = 0; j < 2; j++){
        acc_c[i][j] = __builtin_amdgcn_mfma_f32_16x16x32_bf16(au[i], bc2[j], acc_c[i][j], 0,0,0);
        acc_p[i][j] = __builtin_amdgcn_mfma_f32_16x16x32_bf16(ah[i], bp2[j], acc_p[i][j], 0,0,0);
        acc_z[i][j] = __builtin_amdgcn_mfma_f32_16x16x32_bf16(ah[i], bz2[j], acc_z[i][j], 0,0,0);
      }
    __builtin_amdgcn_s_setprio(0);
    read_frags(a1, 1, au, ah, bc2, bp2, bz2);
    WAIT_LGKM0; SCHEDB; SBAR;          // all waves done reading both halves
    if (2*it + 2 < 16) stageB(0, 2*it + 2);
    if (2*it + 3 < 16) stageB(1, 2*it + 3);
    if (2*it + 3 < 16) stageA(a0, 2*it + 3);   // (2it+3)%3 == a0
    if (2*it + 4 < 16) stageA(a1, 2*it + 4);   // (2it+4)%3 == a1
    __builtin_amdgcn_s_setprio(1);
    #pragma unroll
    for (int i = 0; i < 4; i++)
      #pragma unroll
      for (int j = 0; j < 2; j++){
        acc_c[i][j] = __builtin_amdgcn_mfma_f32_16x16x32_bf16(au[i], bc2[j], acc_c[i][j], 0,0,0);
        acc_p[i][j] = __builtin_amdgcn_mfma_f32_16x16x32_bf16(ah[i], bp2[j], acc_p[i][j], 0,0,0);
        acc_z[i][j] = __builtin_amdgcn_mfma_f32_16x16x32_bf16(ah[i], bz2[j], acc_z[i][j], 0,0,0);
      }
    __builtin_amdgcn_s_setprio(0);
    if (2*it + 4 < 16){ WAIT_VM(4); } else { WAIT_VM(0); }
    SCHEDB; SBAR;
  }

  #pragma unroll
  for (int i = 0; i < 4; i++)
    #pragma unroll
    for (int j = 0; j < 2; j++){
      const int col = n0 + wc*32 + j*16 + fr;     // 0..511
      #pragma unroll
      for (int r = 0; r < 4; r++){
        const int m = m0 + wr*64 + i*16 + fq*4 + r;
        const int t = m >> 3, b = m & 7;
        const int node = s + 2*t + z;
        const size_t crow = (size_t)node*8 + b;
        const float cell = tanh_(acc_c[i][j][r] + bf2f(Cx[crow*512 + col]));
        const float zp   = sigm(acc_p[i][j][r] + bf2f(Gx[crow*1536 + 512  + col]));
        const float zv   = sigm(acc_z[i][j][r] + bf2f(Gx[crow*1536 + 1024 + col]));
        // parent h: for node = s+2t+z, parent_local = t -> Hprev row = t*8+b = m
        const float ph = bf2f(Hprev[(size_t)m*512 + col]);
        const float h  = zp*ph + zv*cell;
        out[((size_t)b*NNODES + node - 1)*HD + col] = h;
        if (writeH) Hcur[(size_t)((2*t + z)*8 + b)*512 + col] = f2bf(h);
      }
    }
}

// ---- root: h0 = sigm(gx_z) * tanh(cx) ----
__global__ void root_k(const ushort_t* __restrict__ Gx, const ushort_t* __restrict__ Cx,
                       float* __restrict__ out, ushort_t* __restrict__ H0)
{
  const int b = blockIdx.x, c = threadIdx.x;
  float zv   = sigm(bf2f(Gx[(size_t)b*1536 + 1024 + c]));
  float cell = tanh_(bf2f(Cx[(size_t)b*512 + c]));
  float h = zv * cell;
  out[((size_t)b*NNODES + (NNODES-1))*HD + c] = h;
  out[(size_t)BATCH*NNODES*HD + (size_t)b*HD + c] = h;
  H0[(size_t)b*512 + c] = f2bf(h);
}

// ---- small levels (d=1..6): 8-way K-split, 1024-thread blocks ----
// Parent h read from Hprev (bf16, coalesced): node = s+t -> H-row (t>>1)*8+b.
__global__ __launch_bounds__(1024)
void small_gates2(const ushort_t* __restrict__ Hprev, const ushort_t* __restrict__ Gx,
    const float* __restrict__ Wg_l, const float* __restrict__ Wg_r,
    float* __restrict__ G, float* __restrict__ Uf, int s)
{
  __shared__ float PHl[8][512];        // 16KB
  __shared__ float red[8][8][128];     // 32KB: [ks][b][colq]
  const int t = blockIdx.x, node = s + t;
  const int tid  = threadIdx.x;        // 0..1023
  const int colq = tid & 127;
  const int ks   = tid >> 7;           // 0..7
  const int col  = blockIdx.y*128 + colq;   // 0..1535
  const int prow0 = (t >> 1)*8;        // parent H base row
  for (int idx = tid; idx < 8*512; idx += 1024){
    int b = idx >> 9, k = idx & 511;
    PHl[b][k] = bf2f(Hprev[(size_t)(prow0 + b)*512 + k]);
  }
  __syncthreads();
  const float* Whh = (node & 1) ? Wg_l : Wg_r;
  float acc[8] = {};
  const int k0 = ks << 6;              // ks*64
  #pragma unroll 8
  for (int k = 0; k < 64; k++){
    float w = Whh[(size_t)(k0 + k)*LDG + col];
    #pragma unroll
    for (int b = 0; b < 8; b++) acc[b] = fmaf(PHl[b][k0 + k], w, acc[b]);
  }
  #pragma unroll
  for (int b = 0; b < 8; b++) red[ks][b][colq] = acc[b];
  __syncthreads();
  if (ks == 0){
    #pragma unroll
    for (int b = 0; b < 8; b++){
      float a = bf2f(Gx[(size_t)(node*8 + b)*1536 + col]);
      #pragma unroll
      for (int q = 0; q < 8; q++) a += red[q][b][colq];
      float g = sigm(a);
      G[((size_t)(t*8 + b))*1536 + col] = g;
      if (col < 512) Uf[((size_t)(t*8 + b))*512 + col] = g * PHl[b][col];
    }
  }
}

__global__ __launch_bounds__(1024)
void small_cell2(float* __restrict__ out, const ushort_t* __restrict__ Cx,
    const float* __restrict__ Wc_l, const float* __restrict__ Wc_r,
    const float* __restrict__ G, const float* __restrict__ Uf,
    const ushort_t* __restrict__ Hprev, ushort_t* __restrict__ Hcur, int s)
{
  __shared__ float Ul[8][512];         // 16KB
  __shared__ float red[8][8][128];     // 32KB
  const int t = blockIdx.x, node = s + t;
  const int tid  = threadIdx.x;
  const int colq = tid & 127;
  const int ks   = tid >> 7;
  const int col  = blockIdx.y*128 + colq;   // 0..511
  for (int idx = tid; idx < 8*512; idx += 1024){
    int b = idx >> 9, k = idx & 511;
    Ul[b][k] = Uf[((size_t)(t*8 + b))*512 + k];
  }
  __syncthreads();
  const float* Whh = (node & 1) ? Wc_l : Wc_r;
  float acc[8] = {};
  const int k0 = ks << 6;
  #pragma unroll 8
  for (int k = 0; k < 64; k++){
    float w = Whh[(size_t)(k0 + k)*HD + col];
    #pragma unroll
    for (int b = 0; b < 8; b++) acc[b] = fmaf(Ul[b][k0 + k], w, acc[b]);
  }
  #pragma unroll
  for (int b = 0; b < 8; b++) red[ks][b][colq] = acc[b];
  __syncthreads();
  if (ks == 0){
    const int prow0 = (t >> 1)*8;      // parent H base row
    #pragma unroll
    for (int b = 0; b < 8; b++){
      float a = bf2f(Cx[(size_t)(node*8 + b)*512 + col]);
      #pragma unroll
      for (int q = 0; q < 8; q++) a += red[q][b][colq];
      float zp = G[((size_t)(t*8 + b))*1536 + 512  + col];
      float zv = G[((size_t)(t*8 + b))*1536 + 1024 + col];
      float ph = bf2f(Hprev[(size_t)(prow0 + b)*512 + col]);
      float h  = zp*ph + zv*tanh_(a);
      out[((size_t)b*NNODES + (node - 1))*HD + col] = h;
      Hcur[(size_t)(t*8 + b)*512 + col] = f2bf(h);
    }
  }
}

// =======================================================================
//      FALLBACK (no ws): round-1 fused level kernel — practically unused
// =======================================================================
__device__ __forceinline__ void unpack8(uint4 u, float v[8]){
  v[0]=bf2f((unsigned short)(u.x & 0xffffu)); v[1]=bf2f((unsigned short)(u.x >> 16));
  v[2]=bf2f((unsigned short)(u.y & 0xffffu)); v[3]=bf2f((unsigned short)(u.y >> 16));
  v[4]=bf2f((unsigned short)(u.z & 0xffffu)); v[5]=bf2f((unsigned short)(u.z >> 16));
  v[6]=bf2f((unsigned short)(u.w & 0xffffu)); v[7]=bf2f((unsigned short)(u.w >> 16));
}
__device__ __forceinline__ void gemm_acc(const unsigned short* Al0,
                                         const unsigned short* Al1,
                                         const float* __restrict__ W,
                                         int ldw, int c0, float acc[2][16])
{
  const float* wr = W + c0;
  #pragma unroll 2
  for (int k0 = 0; k0 < 512; k0 += 8){
    uint4 u0 = *(const uint4*)(Al0 + k0);
    uint4 u1 = *(const uint4*)(Al1 + k0);
    float a0[8], a1[8];
    unpack8(u0, a0); unpack8(u1, a1);
    #pragma unroll
    for (int kk = 0; kk < 8; kk++){
      float wv[16];
      *(float4*)(wv+ 0) = *(const float4*)(wr+ 0);
      *(float4*)(wv+ 4) = *(const float4*)(wr+ 4);
      *(float4*)(wv+ 8) = *(const float4*)(wr+ 8);
      *(float4*)(wv+12) = *(const float4*)(wr+12);
      wr += ldw;
      float x0 = a0[kk], x1 = a1[kk];
      #pragma unroll
      for (int j = 0; j < 16; j++){
        acc[0][j] = fmaf(x0, wv[j], acc[0][j]);
        acc[1][j] = fmaf(x1, wv[j], acc[1][j]);
      }
    }
  }
}

__global__ __launch_bounds__(256)
void tdtree_level(const float* __restrict__ X, float* __restrict__ out,
    const float* __restrict__ Wg_ih, const float* __restrict__ bg,
    const float* __restrict__ Wg_l,  const float* __restrict__ Wg_r,
    const float* __restrict__ Wc_ih, const float* __restrict__ bc,
    const float* __restrict__ Wc_l,  const float* __restrict__ Wc_r,
    int s, int nodes_p, int isRoot)
{
  __shared__ __align__(16) unsigned short Xl [16][512];
  __shared__ __align__(16) unsigned short PHl[16][512];
  __shared__ __align__(16) unsigned short Ul [16][512];

  const int tid = threadIdx.x;
  const int tx  = tid & 31;
  const int ty  = tid >> 5;
  const int parity = blockIdx.y;
  const float* Wg_hh = parity ? Wg_r : Wg_l;
  const float* Wc_hh = parity ? Wc_r : Wc_l;
  const int t0 = blockIdx.x * 2;

  for (int idx = tid; idx < 16*512; idx += 256){
    int m = idx >> 9, k = idx & 511;
    int t = t0 + (m >> 3), b = m & 7;
    float xv = 0.f, pv = 0.f;
    if (t < nodes_p){
      int node = isRoot ? 0 : (s + 2*t + parity);
      xv = X[((size_t)b*NNODES + node)*ID + k];
      if (!isRoot){
        int pnode = (node - 1) >> 1;
        int pslot = pnode ? (pnode - 1) : (NNODES - 1);
        pv = out[((size_t)b*NNODES + pslot)*HD + k];
      }
    }
    Xl[m][k]  = f2bf(xv);
    PHl[m][k] = f2bf(pv);
  }
  __syncthreads();

  const int r0 = ty*2, r1 = r0 + 1;
  const int c  = tx*16;
  const unsigned short* Ax0 = &Xl[r0][0];
  const unsigned short* Ax1 = &Xl[r1][0];
  const unsigned short* Ap0 = &PHl[r0][0];
  const unsigned short* Ap1 = &PHl[r1][0];
  float acc[2][16], cell[2][16];

  #pragma unroll
  for (int j=0;j<16;j++){ float bv = bg[c+j]; acc[0][j]=bv; acc[1][j]=bv; }
  gemm_acc(Ax0, Ax1, Wg_ih, LDG, c, acc);
  if (!isRoot) gemm_acc(Ap0, Ap1, Wg_hh, LDG, c, acc);
  #pragma unroll
  for (int j=0;j<16;j++){
    Ul[r0][c+j] = f2bf(sigm(acc[0][j]) * bf2f(PHl[r0][c+j]));
    Ul[r1][c+j] = f2bf(sigm(acc[1][j]) * bf2f(PHl[r1][c+j]));
  }
  __syncthreads();

  #pragma unroll
  for (int j=0;j<16;j++){ float bv = bc[c+j]; cell[0][j]=bv; cell[1][j]=bv; }
  gemm_acc(Ax0, Ax1, Wc_ih, HD, c, cell);
  if (!isRoot) gemm_acc(&Ul[r0][0], &Ul[r1][0], Wc_hh, HD, c, cell);
  #pragma unroll
  for (int j=0;j<16;j++){ cell[0][j] = tanh_(cell[0][j]); cell[1][j] = tanh_(cell[1][j]); }

  #pragma unroll
  for (int j=0;j<16;j++){ float bv = bg[1024+c+j]; acc[0][j]=bv; acc[1][j]=bv; }
  gemm_acc(Ax0, Ax1, Wg_ih, LDG, 1024+c, acc);
  if (!isRoot) gemm_acc(Ap0, Ap1, Wg_hh, LDG, 1024+c, acc);
  #pragma unroll
  for (int j=0;j<16;j++){ cell[0][j] *= sigm(acc[0][j]); cell[1][j] *= sigm(acc[1][j]); }

  #pragma unroll
  for (int j=0;j<16;j++){ float bv = bg[512+c+j]; acc[0][j]=bv; acc[1][j]=bv; }
  gemm_acc(Ax0, Ax1, Wg_ih, LDG, 512+c, acc);
  if (!isRoot) gemm_acc(Ap0, Ap1, Wg_hh, LDG, 512+c, acc);

  #pragma unroll
  for (int i=0;i<2;i++){
    int m = r0 + i;
    int t = t0 + (m >> 3), b = m & 7;
    if (t >= nodes_p) continue;
    int node = isRoot ? 0 : (s + 2*t + parity);
    int slot = node ? (node - 1) : (NNODES - 1);
    float* op = out + ((size_t)b*NNODES + slot)*HD + c;
    float hv[16];
    if (isRoot){
      #pragma unroll
      for (int j=0;j<16;j++) hv[j] = cell[i][j];
    } else {
      int pnode = (node - 1) >> 1;
      int pslot = pnode ? (pnode - 1) : (NNODES - 1);
      const float* pp = out + ((size_t)b*NNODES + pslot)*HD + c;
      #pragma unroll
      for (int j=0;j<16;j++) hv[j] = sigm(acc[i][j]) * pp[j] + cell[i][j];
    }
    #pragma unroll
    for (int q=0;q<4;q++) *(float4*)(op + q*4) = *(const float4*)(hv + q*4);
    if (isRoot){
      float* o2 = out + (size_t)BATCH*NNODES*HD + (size_t)b*HD + c;
      #pragma unroll
      for (int q=0;q<4;q++) *(float4*)(o2 + q*4) = *(const float4*)(hv + q*4);
    }
  }
}

// =======================================================================
//                              host
// =======================================================================
extern "C" void kernel_launch(void* const* d_in, const int* in_sizes, int n_in,
                              void* d_out, int out_size, void* d_ws, size_t ws_size,
                              hipStream_t stream)
{
  const float* X     = (const float*)d_in[0];
  const float* Wg_ih = (const float*)d_in[2];
  const float* bg    = (const float*)d_in[3];
  const float* Wg_l  = (const float*)d_in[4];
  const float* Wg_r  = (const float*)d_in[5];
  const float* Wc_ih = (const float*)d_in[6];
  const float* bc    = (const float*)d_in[7];
  const float* Wc_l  = (const float*)d_in[8];
  const float* Wc_r  = (const float*)d_in[9];
  float* out = (float*)d_out;
  char* ws = (char*)d_ws;

  // ---------------- ws layout ----------------
  size_t o = 0;
  ushort_t* WgTih = (ushort_t*)(ws + o); o += (size_t)1536*512*2;
  ushort_t* WcTih = (ushort_t*)(ws + o); o += (size_t)512*512*2;
  ushort_t* WgThh = (ushort_t*)(ws + o); o += (size_t)3072*512*2;
  ushort_t* WcThh = (ushort_t*)(ws + o); o += (size_t)1024*512*2;
  ushort_t* Gxp   = (ushort_t*)(ws + o); o += (size_t)32768*1536*2;
  ushort_t* Cxp   = (ushort_t*)(ws + o); o += (size_t)32768*512*2;
  ushort_t* Hb0   = (ushort_t*)(ws + o); o += (size_t)MAXR*512*2;
  ushort_t* Hb1   = (ushort_t*)(ws + o); o += (size_t)MAXR*512*2;
  char*     BIG   = ws + o;              o += (size_t)32768*512*2;  // Abf (hoist) / Ubuf (levels)
  float*    Gs    = (float*)(ws + o);    o += (size_t)512*1536*4;   // d<=6: count*8 <= 512 rows
  float*    Us    = (float*)(ws + o);    o += (size_t)512*512*4;
  const size_t NEED = o;

  if (ws_size >= NEED){
    ushort_t* Abf  = (ushort_t*)BIG;   // [32760][512] during hoist
    ushort_t* Ubuf = (ushort_t*)BIG;   // [2][MAXR][512] during levels

    // merged: gather_X (16380 blocks) + prep_all (1152 blocks), independent
    prep_gather<<<dim3(16380 + 1152), 256, 0, stream>>>(
        X, Abf, Wg_ih, Wc_ih, Wg_l, Wg_r, Wc_l, Wc_r,
        WgTih, WcTih, WgThh, WcThh);
    gemm_hoist<<<dim3(1024), 512, 0, stream>>>(Abf, WgTih, bg, Gxp, WcTih, bc, Cxp);

    root_k<<<dim3(8), 512, 0, stream>>>(Gxp, Cxp, out, Hb0);

    for (int d = 1; d < 12; ++d){
      const int count = 1 << d, s = count - 1;
      ushort_t* Hprev = ((d-1) & 1) ? Hb1 : Hb0;
      ushort_t* Hcur  = (d & 1) ? Hb1 : Hb0;
      if (d < 7){
        small_gates2<<<dim3(count,12), 1024, 0, stream>>>(Hprev, Gxp, Wg_l, Wg_r, Gs, Us, s);
        small_cell2 <<<dim3(count,4),  1024, 0, stream>>>(out, Cxp, Wc_l, Wc_r, Gs, Us, Hprev, Hcur, s);
      } else {
        const int mt = 1 << (d - 5);     // Mp/128
        gates_rp <<<dim3(mt*8),  256, 0, stream>>>(Hprev, WgThh, Gxp, Ubuf, s);
        cell_comb<<<dim3(mt*16), 256, 0, stream>>>(Ubuf, Hprev, WcThh, WgThh,
                                                   Gxp, Cxp, out, Hcur, s, d < 11);
      }
    }
    return;
  }

  // ---------------- fallback: no-ws fused path ----------------
  for (int d = 0; d < 12; ++d){
    const int count  = 1 << d;
    const int snode  = count - 1;
    const int isRoot = (d == 0);
    const int nodes_p = isRoot ? 1 : (count >> 1);
    const int blocks  = (nodes_p + 1) >> 1;
    dim3 grid(blocks, isRoot ? 1 : 2);
    tdtree_level<<<grid, 256, 0, stream>>>(X, out, Wg_ih, bg, Wg_l, Wg_r,
                                           Wc_ih, bc, Wc_l, Wc_r,
                                           snode, nodes_p, isRoot);
  }
}